// Round 2
// baseline (544.579 us; speedup 1.0000x reference)
//
#include <hip/hip_runtime.h>

typedef unsigned int uint32;
typedef unsigned short ushort_t;

#define BATCH 4
#define DI    192   // d_inner == d_model
#define KKDIR 4
#define NS    16    // d_state
#define RK    12    // dt_rank
#define LLEN  4096  // H*W
#define CDBL  44    // RK + 2*NS
#define NCH   64    // scan chunks
#define CLEN  64    // chunk length
#define BLD   ((size_t)BATCH*LLEN*DI)

__device__ __forceinline__ float bf2f(ushort_t u){
  union { uint32 i; float f; } v; v.i = ((uint32)u) << 16; return v.f;
}
__device__ __forceinline__ ushort_t f2bf(float f){
  union { float f; uint32 i; } v; v.f = f;
  return (ushort_t)((v.i + 0x7fffu + ((v.i >> 16) & 1u)) >> 16);
}
// dual-dtype loads: BF=true -> packed bf16, BF=false -> fp32
template<bool BF> __device__ __forceinline__ float ld1(const void* p, size_t i){
  if(BF) return bf2f(((const ushort_t*)p)[i]);
  return ((const float*)p)[i];
}
template<bool BF> __device__ __forceinline__ float4 ld4(const void* p, size_t i){
  if(BF){
    uint2 w = *(const uint2*)(((const ushort_t*)p) + i);
    return make_float4(bf2f((ushort_t)(w.x & 0xffffu)), bf2f((ushort_t)(w.x >> 16)),
                       bf2f((ushort_t)(w.y & 0xffffu)), bf2f((ushort_t)(w.y >> 16)));
  }
  return *(const float4*)(((const float*)p) + i);
}
template<bool BF> __device__ __forceinline__ void stout(void* p, size_t i, float v){
  if(BF) ((ushort_t*)p)[i] = f2bf(v);
  else   ((float*)p)[i] = v;
}
// direction k: sequence position l reads spatial (row-major) position permk(k,l); involution
__device__ __forceinline__ int permk(int k, int l){
  if(k == 0) return l;
  if(k == 1) return ((l & 63) << 6) | (l >> 6);
  if(k == 2) return 4095 - l;
  int m = 4095 - l;
  return ((m & 63) << 6) | (m >> 6);
}
__device__ __forceinline__ float softplusf(float a){
  return fmaxf(a, 0.f) + log1pf(__expf(-fabsf(a)));
}

// ---------------- K0: dtype detect (A_logs[0]==log(1)==0.0f iff fp32) ----------------
__global__ void k_detect(const void* alog, uint32* flag){
  if(threadIdx.x == 0 && blockIdx.x == 0)
    *flag = (*(const uint32*)alog != 0u) ? 1u : 0u;
}

// ---------------- K1: input projection  Xout[b,l,d] = sum_c X[b,c,l]*W[c,d] ----------------
template<bool BF>
__device__ void inproj_impl(const void* X, const void* Wm, float* Xout, float (*xs)[64]){
  const int b  = blockIdx.x >> 6;
  const int l0 = (blockIdx.x & 63) << 6;
  const int t  = threadIdx.x;
  for(int idx = t; idx < DI*64; idx += 256){
    int c = idx >> 6, lc = idx & 63;
    xs[c][lc] = ld1<BF>(X, (size_t)(b*DI + c)*LLEN + l0 + lc);
  }
  __syncthreads();
  #pragma unroll
  for(int it = 0; it < 3; ++it){
    int item = it*256 + t;      // 48 d-groups x 16 l-groups
    int dg = item % 48;
    int lg = item / 48;
    float a00=0,a01=0,a02=0,a03=0,a10=0,a11=0,a12=0,a13=0;
    float a20=0,a21=0,a22=0,a23=0,a30=0,a31=0,a32=0,a33=0;
    #pragma unroll 4
    for(int c = 0; c < DI; ++c){
      float4 w = ld4<BF>(Wm, (size_t)c*DI + dg*4);
      float4 xv = *(const float4*)&xs[c][lg*4];
      a00 += xv.x*w.x; a01 += xv.x*w.y; a02 += xv.x*w.z; a03 += xv.x*w.w;
      a10 += xv.y*w.x; a11 += xv.y*w.y; a12 += xv.y*w.z; a13 += xv.y*w.w;
      a20 += xv.z*w.x; a21 += xv.z*w.y; a22 += xv.z*w.z; a23 += xv.z*w.w;
      a30 += xv.w*w.x; a31 += xv.w*w.y; a32 += xv.w*w.z; a33 += xv.w*w.w;
    }
    size_t rb = ((size_t)b*LLEN + l0 + lg*4)*DI + dg*4;
    *(float4*)(Xout + rb)        = make_float4(a00,a01,a02,a03);
    *(float4*)(Xout + rb + DI)   = make_float4(a10,a11,a12,a13);
    *(float4*)(Xout + rb + 2*DI) = make_float4(a20,a21,a22,a23);
    *(float4*)(Xout + rb + 3*DI) = make_float4(a30,a31,a32,a33);
  }
}
__global__ __launch_bounds__(256) void k_inproj(const void* X, const void* Wm,
                                                float* Xout, const uint32* flag){
  __shared__ float xs[DI][64];
  if(*flag) inproj_impl<true>(X, Wm, Xout, xs);
  else      inproj_impl<false>(X, Wm, Xout, xs);
}

// ---------------- K2: per-location direction projections -> dtsP, B/C ----------------
template<bool BF>
__device__ void proj_impl(const float* Xin, const void* Wp,
                          float* dtsP, float* BC,
                          float (*xr)[204], float (*Pl)[17]){
  const int b  = blockIdx.x >> 8;
  const int p0 = (blockIdx.x & 255) << 4;
  const int t  = threadIdx.x;
  for(int idx = t; idx < 16*DI; idx += 256){
    int pl = idx / DI, d = idx % DI;
    xr[pl][d] = Xin[((size_t)b*LLEN + p0 + pl)*DI + d];
  }
  __syncthreads();
  // P[k][c][pl] = dot(x_row, Wp[k][c][:]) : 4*44*16 = 2816 items
  #pragma unroll
  for(int it = 0; it < 11; ++it){
    int item = it*256 + t;
    int pl = item & 15;
    int kc = item >> 4;
    float acc = 0.f;
    #pragma unroll 4
    for(int j = 0; j < DI/4; ++j){
      float4 w = ld4<BF>(Wp, (size_t)kc*DI + j*4);
      float4 xv = *(const float4*)&xr[pl][j*4];
      acc += xv.x*w.x + xv.y*w.y + xv.z*w.z + xv.w*w.w;
    }
    Pl[kc][pl] = acc;
  }
  __syncthreads();
  // store dts rows: 16 pl x 4 k x 12 r = 768
  {
    int item = t;
    for(int it = 0; it < 3; ++it, item += 256){
      int pl  = item / 48;
      int rem = item % 48;
      int k = rem / RK, r = rem % RK;
      dtsP[(((size_t)b*KKDIR + k)*LLEN + p0 + pl)*RK + r] = Pl[k*CDBL + r][pl];
    }
  }
  // store B/C: 16 pl x 4 k x 32 c = 2048
  #pragma unroll
  for(int it = 0; it < 8; ++it){
    int item = it*256 + t;
    int pl  = item >> 7;
    int rem = item & 127;
    int k = rem >> 5, c2 = rem & 31;
    BC[(((size_t)b*KKDIR + k)*LLEN + p0 + pl)*32 + c2] = Pl[k*CDBL + 12 + c2][pl];
  }
}
__global__ __launch_bounds__(256) void k_proj(const float* Xin, const void* Wp,
                                              float* dtsP, float* BC, const uint32* flag){
  __shared__ float xr[16][204];
  __shared__ float Pl[KKDIR*CDBL][17];
  if(*flag) proj_impl<true>(Xin, Wp, dtsP, BC, xr, Pl);
  else      proj_impl<false>(Xin, Wp, dtsP, BC, xr, Pl);
}

// ---------------- K3a: chunked scan phase 1 (local scan from h=0; store S, decay P) --------
template<bool BF>
__device__ void scan1_impl(const float* dtsP, const float* Yin, const float* BC,
                           const void* Alog, const void* Wdt, const void* biasw,
                           float* Sarr, float* Parr,
                           float (*bs)[NS], float (*pr)[RK]){
  const int blk = blockIdx.x;
  const int ch = blk % NCH;
  const int bk = blk / NCH;   // b*K + k
  const int k  = bk % KKDIR;
  const int b  = bk / KKDIR;
  const int d  = threadIdx.x;
  const int l0 = ch * CLEN;
  for(int idx = threadIdx.x; idx < CLEN*NS; idx += 192){
    int j = idx >> 4, n = idx & 15;
    int p = permk(k, l0 + j);
    bs[j][n] = BC[((size_t)bk*LLEN + p)*32 + n];
  }
  for(int idx = threadIdx.x; idx < CLEN*RK; idx += 192){
    int j = idx / RK, r = idx - j*RK;
    int p = permk(k, l0 + j);
    pr[j][r] = dtsP[((size_t)bk*LLEN + p)*RK + r];
  }
  float as2[NS];
  {
    size_t arow = (size_t)(k*DI + d)*NS;
    #pragma unroll
    for(int n = 0; n < NS; ++n) as2[n] = -__expf(ld1<BF>(Alog, arow + n)) * 1.44269504f;
  }
  float wv[RK];
  {
    size_t wrow = (size_t)(k*DI + d)*RK;
    float4 w0 = ld4<BF>(Wdt, wrow), w1 = ld4<BF>(Wdt, wrow+4), w2 = ld4<BF>(Wdt, wrow+8);
    wv[0]=w0.x; wv[1]=w0.y; wv[2]=w0.z; wv[3]=w0.w;
    wv[4]=w1.x; wv[5]=w1.y; wv[6]=w1.z; wv[7]=w1.w;
    wv[8]=w2.x; wv[9]=w2.y; wv[10]=w2.z; wv[11]=w2.w;
  }
  const float bv = ld1<BF>(biasw, k*DI + d);
  float h[NS];
  #pragma unroll
  for(int n = 0; n < NS; ++n) h[n] = 0.f;
  float sdt = 0.f;
  __syncthreads();
  const float* yrow = Yin + (size_t)b*LLEN*DI + d;
  for(int j = 0; j < CLEN; ++j){
    int p = permk(k, l0 + j);
    float a = bv;
    #pragma unroll
    for(int r = 0; r < RK; ++r) a += pr[j][r]*wv[r];
    float dt = softplusf(a);
    float u  = yrow[(size_t)p*DI];
    sdt += dt;
    float dtu = dt*u;
    #pragma unroll
    for(int n = 0; n < NS; ++n){
      float e = __builtin_amdgcn_exp2f(dt*as2[n]);
      h[n] = e*h[n] + dtu*bs[j][n];
    }
  }
  size_t base = ((size_t)(bk*DI + d)*NCH + ch)*NS;
  #pragma unroll
  for(int n = 0; n < NS; ++n){
    Sarr[base+n] = h[n];
    Parr[base+n] = __builtin_amdgcn_exp2f(as2[n]*sdt);
  }
}
__global__ __launch_bounds__(192) void k_scan1(const float* dtsP, const float* Yin,
                                               const float* BC, const void* Alog,
                                               const void* Wdt, const void* biasw,
                                               float* Sarr, float* Parr, const uint32* flag){
  __shared__ float bs[CLEN][NS];
  __shared__ float pr[CLEN][RK];
  if(*flag) scan1_impl<true>(dtsP, Yin, BC, Alog, Wdt, biasw, Sarr, Parr, bs, pr);
  else      scan1_impl<false>(dtsP, Yin, BC, Alog, Wdt, biasw, Sarr, Parr, bs, pr);
}

// ---------------- K3b: cross-chunk prefix (in-place: Sarr becomes h_in per chunk) -------------
__global__ __launch_bounds__(256) void k_scan2(float* __restrict__ Sarr,
                                               const float* __restrict__ Parr){
  int tid = blockIdx.x*256 + threadIdx.x;   // 49152 = B*K*D*N
  int n = tid & 15;
  int bkd = tid >> 4;
  float h = 0.f;
  for(int c = 0; c < NCH; ++c){
    size_t i = ((size_t)bkd*NCH + c)*NS + n;
    float s = Sarr[i], p = Parr[i];
    Sarr[i] = h;
    h = p*h + s;
  }
}

// ---------------- K3c: scan phase 3 (with h_in; atomic-accumulate y at spatial pos) -----------
template<bool BF>
__device__ void scan3_impl(const float* dtsP, const float* Yin, const float* BC,
                           const void* Alog, const void* Wdt, const void* biasw,
                           const void* DsI, const float* Hin, float* Acc,
                           float (*bs)[32], float (*pr)[RK]){
  const int blk = blockIdx.x;
  const int ch = blk % NCH;
  const int bk = blk / NCH;
  const int k  = bk % KKDIR;
  const int b  = bk / KKDIR;
  const int d  = threadIdx.x;
  const int l0 = ch * CLEN;
  for(int idx = threadIdx.x; idx < CLEN*32; idx += 192){
    int j = idx >> 5, n = idx & 31;
    int p = permk(k, l0 + j);
    bs[j][n] = BC[((size_t)bk*LLEN + p)*32 + n];
  }
  for(int idx = threadIdx.x; idx < CLEN*RK; idx += 192){
    int j = idx / RK, r = idx - j*RK;
    int p = permk(k, l0 + j);
    pr[j][r] = dtsP[((size_t)bk*LLEN + p)*RK + r];
  }
  float as2[NS];
  {
    size_t arow = (size_t)(k*DI + d)*NS;
    #pragma unroll
    for(int n = 0; n < NS; ++n) as2[n] = -__expf(ld1<BF>(Alog, arow + n)) * 1.44269504f;
  }
  float wv[RK];
  {
    size_t wrow = (size_t)(k*DI + d)*RK;
    float4 w0 = ld4<BF>(Wdt, wrow), w1 = ld4<BF>(Wdt, wrow+4), w2 = ld4<BF>(Wdt, wrow+8);
    wv[0]=w0.x; wv[1]=w0.y; wv[2]=w0.z; wv[3]=w0.w;
    wv[4]=w1.x; wv[5]=w1.y; wv[6]=w1.z; wv[7]=w1.w;
    wv[8]=w2.x; wv[9]=w2.y; wv[10]=w2.z; wv[11]=w2.w;
  }
  const float bv = ld1<BF>(biasw, k*DI + d);
  const float dsv = ld1<BF>(DsI, k*DI + d);
  float h[NS];
  {
    size_t hbase = ((size_t)(bk*DI + d)*NCH + ch)*NS;
    #pragma unroll
    for(int n = 0; n < NS; ++n) h[n] = Hin[hbase+n];
  }
  __syncthreads();
  const float* yrow = Yin + (size_t)b*LLEN*DI + d;
  float* arow = Acc + (size_t)b*LLEN*DI + d;
  for(int j = 0; j < CLEN; ++j){
    int p = permk(k, l0 + j);
    float a = bv;
    #pragma unroll
    for(int r = 0; r < RK; ++r) a += pr[j][r]*wv[r];
    float dt = softplusf(a);
    float u  = yrow[(size_t)p*DI];
    float dtu = dt*u;
    float y = dsv*u;
    #pragma unroll
    for(int n = 0; n < NS; ++n){
      float e = __builtin_amdgcn_exp2f(dt*as2[n]);
      h[n] = e*h[n] + dtu*bs[j][n];
      y += h[n]*bs[j][16+n];
    }
    atomicAdd(arow + (size_t)p*DI, y);   // permk is an involution: seq l emits at spatial p
  }
}
__global__ __launch_bounds__(192) void k_scan3(const float* dtsP, const float* Yin,
                                               const float* BC, const void* Alog,
                                               const void* Wdt, const void* biasw,
                                               const void* DsI, const float* Hin,
                                               float* Acc, const uint32* flag){
  __shared__ float bs[CLEN][32];
  __shared__ float pr[CLEN][RK];
  if(*flag) scan3_impl<true>(dtsP, Yin, BC, Alog, Wdt, biasw, DsI, Hin, Acc, bs, pr);
  else      scan3_impl<false>(dtsP, Yin, BC, Alog, Wdt, biasw, DsI, Hin, Acc, bs, pr);
}

// ---------------- K4: LayerNorm + out_proj + store ------------------
template<bool BF>
__device__ void post_impl(const float* Acc, const void* gamma, const void* beta,
                          const void* Wout, void* Out,
                          float (*ym)[204], float* mu, float* rs){
  const int b  = blockIdx.x >> 8;
  const int l0 = (blockIdx.x & 255) << 4;
  const int t  = threadIdx.x;
  #pragma unroll
  for(int it = 0; it < 12; ++it){
    int item = it*256 + t;
    int d = item % DI, pl = item / DI;
    ym[pl][d] = Acc[((size_t)b*LLEN + l0 + pl)*DI + d];
  }
  __syncthreads();
  {
    int row = t >> 4, sub = t & 15;
    float s1 = 0.f, s2 = 0.f;
    #pragma unroll
    for(int j = 0; j < 12; ++j){
      float v = ym[row][j*16 + sub];
      s1 += v; s2 += v*v;
    }
    #pragma unroll
    for(int m = 1; m < 16; m <<= 1){
      s1 += __shfl_xor(s1, m, 64);
      s2 += __shfl_xor(s2, m, 64);
    }
    if(sub == 0){
      float mean = s1 * (1.f/192.f);
      float var = s2 * (1.f/192.f) - mean*mean;
      mu[row] = mean;
      rs[row] = rsqrtf(var + 1e-5f);
    }
  }
  __syncthreads();
  #pragma unroll
  for(int it = 0; it < 12; ++it){
    int item = it*256 + t;
    int d = item % DI, pl = item / DI;
    float v = (ym[pl][d] - mu[pl]) * rs[pl];
    ym[pl][d] = v * ld1<BF>(gamma, d) + ld1<BF>(beta, d);
  }
  __syncthreads();
  {
    int pl = t & 15, cg = t >> 4;   // 16 c-groups of 12
    float acc[12];
    #pragma unroll
    for(int j = 0; j < 12; ++j) acc[j] = 0.f;
    for(int dd = 0; dd < DI; ++dd){
      float v = ym[pl][dd];
      size_t wrow = (size_t)dd*DI + cg*12;
      float4 w0 = ld4<BF>(Wout, wrow), w1 = ld4<BF>(Wout, wrow+4), w2 = ld4<BF>(Wout, wrow+8);
      acc[0]  += v*w0.x; acc[1]  += v*w0.y; acc[2]  += v*w0.z; acc[3]  += v*w0.w;
      acc[4]  += v*w1.x; acc[5]  += v*w1.y; acc[6]  += v*w1.z; acc[7]  += v*w1.w;
      acc[8]  += v*w2.x; acc[9]  += v*w2.y; acc[10] += v*w2.z; acc[11] += v*w2.w;
    }
    #pragma unroll
    for(int j = 0; j < 12; ++j){
      int c = cg*12 + j;
      stout<BF>(Out, ((size_t)b*DI + c)*LLEN + l0 + pl, acc[j]);
    }
  }
}
__global__ __launch_bounds__(256) void k_post(const float* Acc, const void* gamma,
                                              const void* beta, const void* Wout,
                                              void* Out, const uint32* flag){
  __shared__ float ym[16][204];
  __shared__ float mu[16], rs[16];
  if(*flag) post_impl<true>(Acc, gamma, beta, Wout, Out, ym, mu, rs);
  else      post_impl<false>(Acc, gamma, beta, Wout, Out, ym, mu, rs);
}

extern "C" void kernel_launch(void* const* d_in, const int* in_sizes, int n_in,
                              void* d_out, int out_size, void* d_ws, size_t ws_size,
                              hipStream_t stream){
  (void)in_sizes; (void)n_in; (void)out_size; (void)ws_size;
  const void* x    = d_in[0];
  const void* y    = d_in[1];
  const void* wx   = d_in[2];
  const void* wy   = d_in[3];
  const void* xpw  = d_in[4];
  const void* wdt  = d_in[5];
  const void* dtb  = d_in[6];
  const void* alog = d_in[7];
  const void* dsv  = d_in[8];
  const void* gam  = d_in[9];
  const void* bet  = d_in[10];
  const void* wout = d_in[11];

  float* ws   = (float*)d_ws;
  uint32* flag = (uint32*)ws;                                  // 16-float pad
  float* xin  = ws + 16;                                       // BLD
  float* yin  = xin  + BLD;                                    // BLD
  float* dtsP = yin  + BLD;                                    // B*K*L*12
  float* bc   = dtsP + (size_t)BATCH*KKDIR*LLEN*RK;            // B*K*L*32
  float* acc  = bc   + (size_t)BATCH*KKDIR*LLEN*32;            // BLD
  float* sarr = acc  + BLD;                                    // B*K*D*NCH*NS
  float* parr = sarr + (size_t)BATCH*KKDIR*DI*NCH*NS;          // B*K*D*NCH*NS
  // total: 16 + 3*BLD + 0.786M + 2.097M + 2*3.146M floats ~= 74.5 MB

  k_detect<<<1, 64, 0, stream>>>(alog, flag);
  hipMemsetAsync(acc, 0, BLD*sizeof(float), stream);
  k_inproj<<<256, 256, 0, stream>>>(x, wx, xin, flag);
  k_inproj<<<256, 256, 0, stream>>>(y, wy, yin, flag);
  k_proj<<<1024, 256, 0, stream>>>(xin, xpw, dtsP, bc, flag);
  k_scan1<<<BATCH*KKDIR*NCH, 192, 0, stream>>>(dtsP, yin, bc, alog, wdt, dtb, sarr, parr, flag);
  k_scan2<<<192, 256, 0, stream>>>(sarr, parr);
  k_scan3<<<BATCH*KKDIR*NCH, 192, 0, stream>>>(dtsP, yin, bc, alog, wdt, dtb, dsv, sarr, acc, flag);
  k_post<<<1024, 256, 0, stream>>>(acc, gam, bet, wout, d_out, flag);
}

// Round 3
// 426.774 us; speedup vs baseline: 1.2760x; 1.2760x over previous
//
#include <hip/hip_runtime.h>

typedef unsigned int uint32;
typedef unsigned short ushort_t;

#define BATCH 4
#define DI    192   // d_inner == d_model
#define KKDIR 4
#define NS    16    // d_state
#define RK    12    // dt_rank
#define LLEN  4096  // H*W
#define CDBL  44    // RK + 2*NS
#define NCH   64    // scan chunks
#define CLEN  64    // chunk length
#define BLD   ((size_t)BATCH*LLEN*DI)

__device__ __forceinline__ float bf2f(ushort_t u){
  union { uint32 i; float f; } v; v.i = ((uint32)u) << 16; return v.f;
}
__device__ __forceinline__ ushort_t f2bf(float f){
  union { float f; uint32 i; } v; v.f = f;
  return (ushort_t)((v.i + 0x7fffu + ((v.i >> 16) & 1u)) >> 16);
}
// dual-dtype loads: BF=true -> packed bf16, BF=false -> fp32
template<bool BF> __device__ __forceinline__ float ld1(const void* p, size_t i){
  if(BF) return bf2f(((const ushort_t*)p)[i]);
  return ((const float*)p)[i];
}
template<bool BF> __device__ __forceinline__ float4 ld4(const void* p, size_t i){
  if(BF){
    uint2 w = *(const uint2*)(((const ushort_t*)p) + i);
    return make_float4(bf2f((ushort_t)(w.x & 0xffffu)), bf2f((ushort_t)(w.x >> 16)),
                       bf2f((ushort_t)(w.y & 0xffffu)), bf2f((ushort_t)(w.y >> 16)));
  }
  return *(const float4*)(((const float*)p) + i);
}
template<bool BF> __device__ __forceinline__ void stout(void* p, size_t i, float v){
  if(BF) ((ushort_t*)p)[i] = f2bf(v);
  else   ((float*)p)[i] = v;
}
// direction k: sequence position l maps to spatial p = p0(k,l0) + ps(k)*j within an
// aligned 64-chunk (l0 = ch*CLEN, CLEN=64). permk is an involution.
__device__ __forceinline__ int perm_p0(int k, int l0){
  if(k == 0) return l0;
  if(k == 1) return l0 >> 6;
  if(k == 2) return 4095 - l0;
  return 4095 - (l0 >> 6);
}
__device__ __forceinline__ int perm_ps(int k){
  if(k == 0) return 1;
  if(k == 1) return 64;
  if(k == 2) return -1;
  return -64;
}
__device__ __forceinline__ float softplusf(float a){
  return fmaxf(a, 0.f) + __logf(1.f + __expf(-fabsf(a)));
}

// ---------------- K0: dtype detect (A_logs[0]==log(1)==0.0f iff fp32) ----------------
__global__ void k_detect(const void* alog, uint32* flag){
  if(threadIdx.x == 0 && blockIdx.x == 0)
    *flag = (*(const uint32*)alog != 0u) ? 1u : 0u;
}

// ---------------- K1: input projection  Xout[b,l,d] = sum_c X[b,c,l]*W[c,d] ----------------
template<bool BF>
__device__ void inproj_impl(const void* X, const void* Wm, float* Xout, float (*xs)[64]){
  const int b  = blockIdx.x >> 6;
  const int l0 = (blockIdx.x & 63) << 6;
  const int t  = threadIdx.x;
  for(int idx = t; idx < DI*64; idx += 256){
    int c = idx >> 6, lc = idx & 63;
    xs[c][lc] = ld1<BF>(X, (size_t)(b*DI + c)*LLEN + l0 + lc);
  }
  __syncthreads();
  #pragma unroll
  for(int it = 0; it < 3; ++it){
    int item = it*256 + t;      // 48 d-groups x 16 l-groups
    int dg = item % 48;
    int lg = item / 48;
    float a00=0,a01=0,a02=0,a03=0,a10=0,a11=0,a12=0,a13=0;
    float a20=0,a21=0,a22=0,a23=0,a30=0,a31=0,a32=0,a33=0;
    #pragma unroll 4
    for(int c = 0; c < DI; ++c){
      float4 w = ld4<BF>(Wm, (size_t)c*DI + dg*4);
      float4 xv = *(const float4*)&xs[c][lg*4];
      a00 += xv.x*w.x; a01 += xv.x*w.y; a02 += xv.x*w.z; a03 += xv.x*w.w;
      a10 += xv.y*w.x; a11 += xv.y*w.y; a12 += xv.y*w.z; a13 += xv.y*w.w;
      a20 += xv.z*w.x; a21 += xv.z*w.y; a22 += xv.z*w.z; a23 += xv.z*w.w;
      a30 += xv.w*w.x; a31 += xv.w*w.y; a32 += xv.w*w.z; a33 += xv.w*w.w;
    }
    size_t rb = ((size_t)b*LLEN + l0 + lg*4)*DI + dg*4;
    *(float4*)(Xout + rb)        = make_float4(a00,a01,a02,a03);
    *(float4*)(Xout + rb + DI)   = make_float4(a10,a11,a12,a13);
    *(float4*)(Xout + rb + 2*DI) = make_float4(a20,a21,a22,a23);
    *(float4*)(Xout + rb + 3*DI) = make_float4(a30,a31,a32,a33);
  }
}
__global__ __launch_bounds__(256) void k_inproj(const void* X, const void* Wm,
                                                float* Xout, const uint32* flag){
  __shared__ float xs[DI][64];
  if(*flag) inproj_impl<true>(X, Wm, Xout, xs);
  else      inproj_impl<false>(X, Wm, Xout, xs);
}

// ---------------- K2: per-location direction projections -> dtsP, B/C ----------------
template<bool BF>
__device__ void proj_impl(const float* Xin, const void* Wp,
                          float* dtsP, float* BC,
                          float (*xr)[204], float (*Pl)[17]){
  const int b  = blockIdx.x >> 8;
  const int p0 = (blockIdx.x & 255) << 4;
  const int t  = threadIdx.x;
  for(int idx = t; idx < 16*DI; idx += 256){
    int pl = idx / DI, d = idx % DI;
    xr[pl][d] = Xin[((size_t)b*LLEN + p0 + pl)*DI + d];
  }
  __syncthreads();
  // P[k][c][pl] = dot(x_row, Wp[k][c][:]) : 4*44*16 = 2816 items
  #pragma unroll
  for(int it = 0; it < 11; ++it){
    int item = it*256 + t;
    int pl = item & 15;
    int kc = item >> 4;
    float acc = 0.f;
    #pragma unroll 4
    for(int j = 0; j < DI/4; ++j){
      float4 w = ld4<BF>(Wp, (size_t)kc*DI + j*4);
      float4 xv = *(const float4*)&xr[pl][j*4];
      acc += xv.x*w.x + xv.y*w.y + xv.z*w.z + xv.w*w.w;
    }
    Pl[kc][pl] = acc;
  }
  __syncthreads();
  // store dts rows: 16 pl x 4 k x 12 r = 768
  {
    int item = t;
    for(int it = 0; it < 3; ++it, item += 256){
      int pl  = item / 48;
      int rem = item % 48;
      int k = rem / RK, r = rem % RK;
      dtsP[(((size_t)b*KKDIR + k)*LLEN + p0 + pl)*RK + r] = Pl[k*CDBL + r][pl];
    }
  }
  // store B/C: 16 pl x 4 k x 32 c = 2048
  #pragma unroll
  for(int it = 0; it < 8; ++it){
    int item = it*256 + t;
    int pl  = item >> 7;
    int rem = item & 127;
    int k = rem >> 5, c2 = rem & 31;
    BC[(((size_t)b*KKDIR + k)*LLEN + p0 + pl)*32 + c2] = Pl[k*CDBL + 12 + c2][pl];
  }
}
__global__ __launch_bounds__(256) void k_proj(const float* Xin, const void* Wp,
                                              float* dtsP, float* BC, const uint32* flag){
  __shared__ float xr[16][204];
  __shared__ float Pl[KKDIR*CDBL][17];
  if(*flag) proj_impl<true>(Xin, Wp, dtsP, BC, xr, Pl);
  else      proj_impl<false>(Xin, Wp, dtsP, BC, xr, Pl);
}

// ---------------- K3a: chunked scan phase 1; n-split-2 (thread = d*2+nh, 8 states) ----------
template<bool BF>
__device__ void scan1_impl(const float* dtsP, const float* Yin, const float* BC,
                           const void* Alog, const void* Wdt, const void* biasw,
                           float* Sarr, float* Parr,
                           float (*bs)[NS], float (*pr)[RK]){
  const int blk = blockIdx.x;
  const int ch = blk % NCH;
  const int bk = blk / NCH;   // b*K + k
  const int k  = bk % KKDIR;
  const int b  = bk / KKDIR;
  const int t  = threadIdx.x;
  const int d  = t >> 1;
  const int nh = t & 1;       // which 8-state half
  const int l0 = ch * CLEN;
  const int p0 = perm_p0(k, l0);
  const int ps = perm_ps(k);
  for(int idx = t; idx < CLEN*NS; idx += 384){
    int j = idx >> 4, n = idx & 15;
    bs[j][n] = BC[((size_t)bk*LLEN + p0 + ps*j)*32 + n];
  }
  for(int idx = t; idx < CLEN*RK; idx += 384){
    int j = idx / RK, r = idx - j*RK;
    pr[j][r] = dtsP[((size_t)bk*LLEN + p0 + ps*j)*RK + r];
  }
  float as2[8];
  {
    size_t arow = (size_t)(k*DI + d)*NS + nh*8;
    #pragma unroll
    for(int n = 0; n < 8; ++n) as2[n] = -__expf(ld1<BF>(Alog, arow + n)) * 1.44269504f;
  }
  float wv[RK];
  {
    size_t wrow = (size_t)(k*DI + d)*RK;
    float4 w0 = ld4<BF>(Wdt, wrow), w1 = ld4<BF>(Wdt, wrow+4), w2 = ld4<BF>(Wdt, wrow+8);
    wv[0]=w0.x; wv[1]=w0.y; wv[2]=w0.z; wv[3]=w0.w;
    wv[4]=w1.x; wv[5]=w1.y; wv[6]=w1.z; wv[7]=w1.w;
    wv[8]=w2.x; wv[9]=w2.y; wv[10]=w2.z; wv[11]=w2.w;
  }
  const float bv = ld1<BF>(biasw, k*DI + d);
  float h[8];
  #pragma unroll
  for(int n = 0; n < 8; ++n) h[n] = 0.f;
  float sdt = 0.f;
  __syncthreads();
  const float* yrow = Yin + (size_t)b*LLEN*DI + d;
  int p = p0;
  #pragma unroll 2
  for(int j = 0; j < CLEN; ++j){
    float4 q0 = *(const float4*)&pr[j][0];
    float4 q1 = *(const float4*)&pr[j][4];
    float4 q2 = *(const float4*)&pr[j][8];
    float a = bv + q0.x*wv[0] + q0.y*wv[1] + q0.z*wv[2] + q0.w*wv[3]
                 + q1.x*wv[4] + q1.y*wv[5] + q1.z*wv[6] + q1.w*wv[7]
                 + q2.x*wv[8] + q2.y*wv[9] + q2.z*wv[10] + q2.w*wv[11];
    float dt = softplusf(a);
    float u  = yrow[(size_t)p*DI];
    sdt += dt;
    float dtu = dt*u;
    float4 b0 = *(const float4*)&bs[j][nh*8];
    float4 b1 = *(const float4*)&bs[j][nh*8+4];
    h[0] = __builtin_amdgcn_exp2f(dt*as2[0])*h[0] + dtu*b0.x;
    h[1] = __builtin_amdgcn_exp2f(dt*as2[1])*h[1] + dtu*b0.y;
    h[2] = __builtin_amdgcn_exp2f(dt*as2[2])*h[2] + dtu*b0.z;
    h[3] = __builtin_amdgcn_exp2f(dt*as2[3])*h[3] + dtu*b0.w;
    h[4] = __builtin_amdgcn_exp2f(dt*as2[4])*h[4] + dtu*b1.x;
    h[5] = __builtin_amdgcn_exp2f(dt*as2[5])*h[5] + dtu*b1.y;
    h[6] = __builtin_amdgcn_exp2f(dt*as2[6])*h[6] + dtu*b1.z;
    h[7] = __builtin_amdgcn_exp2f(dt*as2[7])*h[7] + dtu*b1.w;
    p += ps;
  }
  size_t base = ((size_t)(bk*DI + d)*NCH + ch)*NS + nh*8;
  *(float4*)(Sarr+base)   = make_float4(h[0],h[1],h[2],h[3]);
  *(float4*)(Sarr+base+4) = make_float4(h[4],h[5],h[6],h[7]);
  float pv[8];
  #pragma unroll
  for(int n = 0; n < 8; ++n) pv[n] = __builtin_amdgcn_exp2f(as2[n]*sdt);
  *(float4*)(Parr+base)   = make_float4(pv[0],pv[1],pv[2],pv[3]);
  *(float4*)(Parr+base+4) = make_float4(pv[4],pv[5],pv[6],pv[7]);
}
__global__ __launch_bounds__(384) void k_scan1(const float* dtsP, const float* Yin,
                                               const float* BC, const void* Alog,
                                               const void* Wdt, const void* biasw,
                                               float* Sarr, float* Parr, const uint32* flag){
  __shared__ float bs[CLEN][NS];
  __shared__ float pr[CLEN][RK];
  if(*flag) scan1_impl<true>(dtsP, Yin, BC, Alog, Wdt, biasw, Sarr, Parr, bs, pr);
  else      scan1_impl<false>(dtsP, Yin, BC, Alog, Wdt, biasw, Sarr, Parr, bs, pr);
}

// ---------------- K3b: cross-chunk prefix (in-place: Sarr becomes h_in per chunk) -------------
__global__ __launch_bounds__(256) void k_scan2(float* __restrict__ Sarr,
                                               const float* __restrict__ Parr){
  int tid = blockIdx.x*256 + threadIdx.x;   // 49152 = B*K*D*N
  int n = tid & 15;
  int bkd = tid >> 4;
  float h = 0.f;
  for(int c = 0; c < NCH; ++c){
    size_t i = ((size_t)bkd*NCH + c)*NS + n;
    float s = Sarr[i], p = Parr[i];
    Sarr[i] = h;
    h = p*h + s;
  }
}

// ---------------- K3c: scan phase 3; n-split-2; atomic-accumulate y at spatial pos -----------
template<bool BF>
__device__ void scan3_impl(const float* dtsP, const float* Yin, const float* BC,
                           const void* Alog, const void* Wdt, const void* biasw,
                           const void* DsI, const float* Hin, float* Acc,
                           float (*bs)[32], float (*pr)[RK]){
  const int blk = blockIdx.x;
  const int ch = blk % NCH;
  const int bk = blk / NCH;
  const int k  = bk % KKDIR;
  const int b  = bk / KKDIR;
  const int t  = threadIdx.x;
  const int d  = t >> 1;
  const int nh = t & 1;
  const int l0 = ch * CLEN;
  const int p0 = perm_p0(k, l0);
  const int ps = perm_ps(k);
  for(int idx = t; idx < CLEN*32; idx += 384){
    int j = idx >> 5, n = idx & 31;
    bs[j][n] = BC[((size_t)bk*LLEN + p0 + ps*j)*32 + n];
  }
  for(int idx = t; idx < CLEN*RK; idx += 384){
    int j = idx / RK, r = idx - j*RK;
    pr[j][r] = dtsP[((size_t)bk*LLEN + p0 + ps*j)*RK + r];
  }
  float as2[8];
  {
    size_t arow = (size_t)(k*DI + d)*NS + nh*8;
    #pragma unroll
    for(int n = 0; n < 8; ++n) as2[n] = -__expf(ld1<BF>(Alog, arow + n)) * 1.44269504f;
  }
  float wv[RK];
  {
    size_t wrow = (size_t)(k*DI + d)*RK;
    float4 w0 = ld4<BF>(Wdt, wrow), w1 = ld4<BF>(Wdt, wrow+4), w2 = ld4<BF>(Wdt, wrow+8);
    wv[0]=w0.x; wv[1]=w0.y; wv[2]=w0.z; wv[3]=w0.w;
    wv[4]=w1.x; wv[5]=w1.y; wv[6]=w1.z; wv[7]=w1.w;
    wv[8]=w2.x; wv[9]=w2.y; wv[10]=w2.z; wv[11]=w2.w;
  }
  const float bv = ld1<BF>(biasw, k*DI + d);
  const float dsv = ld1<BF>(DsI, k*DI + d);
  float h[8];
  {
    size_t hbase = ((size_t)(bk*DI + d)*NCH + ch)*NS + nh*8;
    float4 h0 = *(const float4*)(Hin + hbase);
    float4 h1 = *(const float4*)(Hin + hbase + 4);
    h[0]=h0.x; h[1]=h0.y; h[2]=h0.z; h[3]=h0.w;
    h[4]=h1.x; h[5]=h1.y; h[6]=h1.z; h[7]=h1.w;
  }
  __syncthreads();
  const float* yrow = Yin + (size_t)b*LLEN*DI + d;
  float* arow = Acc + (size_t)b*LLEN*DI + d;
  int p = p0;
  #pragma unroll 2
  for(int j = 0; j < CLEN; ++j){
    float4 q0 = *(const float4*)&pr[j][0];
    float4 q1 = *(const float4*)&pr[j][4];
    float4 q2 = *(const float4*)&pr[j][8];
    float a = bv + q0.x*wv[0] + q0.y*wv[1] + q0.z*wv[2] + q0.w*wv[3]
                 + q1.x*wv[4] + q1.y*wv[5] + q1.z*wv[6] + q1.w*wv[7]
                 + q2.x*wv[8] + q2.y*wv[9] + q2.z*wv[10] + q2.w*wv[11];
    float dt = softplusf(a);
    float u  = yrow[(size_t)p*DI];
    float dtu = dt*u;
    float4 b0 = *(const float4*)&bs[j][nh*8];
    float4 b1 = *(const float4*)&bs[j][nh*8+4];
    float4 c0 = *(const float4*)&bs[j][16+nh*8];
    float4 c1 = *(const float4*)&bs[j][16+nh*8+4];
    float y = (nh == 0) ? dsv*u : 0.f;
    h[0] = __builtin_amdgcn_exp2f(dt*as2[0])*h[0] + dtu*b0.x;  y += h[0]*c0.x;
    h[1] = __builtin_amdgcn_exp2f(dt*as2[1])*h[1] + dtu*b0.y;  y += h[1]*c0.y;
    h[2] = __builtin_amdgcn_exp2f(dt*as2[2])*h[2] + dtu*b0.z;  y += h[2]*c0.z;
    h[3] = __builtin_amdgcn_exp2f(dt*as2[3])*h[3] + dtu*b0.w;  y += h[3]*c0.w;
    h[4] = __builtin_amdgcn_exp2f(dt*as2[4])*h[4] + dtu*b1.x;  y += h[4]*c1.x;
    h[5] = __builtin_amdgcn_exp2f(dt*as2[5])*h[5] + dtu*b1.y;  y += h[5]*c1.y;
    h[6] = __builtin_amdgcn_exp2f(dt*as2[6])*h[6] + dtu*b1.z;  y += h[6]*c1.z;
    h[7] = __builtin_amdgcn_exp2f(dt*as2[7])*h[7] + dtu*b1.w;  y += h[7]*c1.w;
    y += __shfl_xor(y, 1);
    if(nh == 0) atomicAdd(arow + (size_t)p*DI, y);  // involution: seq l emits at spatial p
    p += ps;
  }
}
__global__ __launch_bounds__(384) void k_scan3(const float* dtsP, const float* Yin,
                                               const float* BC, const void* Alog,
                                               const void* Wdt, const void* biasw,
                                               const void* DsI, const float* Hin,
                                               float* Acc, const uint32* flag){
  __shared__ float bs[CLEN][32];
  __shared__ float pr[CLEN][RK];
  if(*flag) scan3_impl<true>(dtsP, Yin, BC, Alog, Wdt, biasw, DsI, Hin, Acc, bs, pr);
  else      scan3_impl<false>(dtsP, Yin, BC, Alog, Wdt, biasw, DsI, Hin, Acc, bs, pr);
}

// ---------------- K4: LayerNorm + out_proj + store ------------------
template<bool BF>
__device__ void post_impl(const float* Acc, const void* gamma, const void* beta,
                          const void* Wout, void* Out,
                          float (*ym)[204], float* mu, float* rs){
  const int b  = blockIdx.x >> 8;
  const int l0 = (blockIdx.x & 255) << 4;
  const int t  = threadIdx.x;
  #pragma unroll
  for(int it = 0; it < 12; ++it){
    int item = it*256 + t;
    int d = item % DI, pl = item / DI;
    ym[pl][d] = Acc[((size_t)b*LLEN + l0 + pl)*DI + d];
  }
  __syncthreads();
  {
    int row = t >> 4, sub = t & 15;
    float s1 = 0.f, s2 = 0.f;
    #pragma unroll
    for(int j = 0; j < 12; ++j){
      float v = ym[row][j*16 + sub];
      s1 += v; s2 += v*v;
    }
    #pragma unroll
    for(int m = 1; m < 16; m <<= 1){
      s1 += __shfl_xor(s1, m, 64);
      s2 += __shfl_xor(s2, m, 64);
    }
    if(sub == 0){
      float mean = s1 * (1.f/192.f);
      float var = s2 * (1.f/192.f) - mean*mean;
      mu[row] = mean;
      rs[row] = rsqrtf(var + 1e-5f);
    }
  }
  __syncthreads();
  #pragma unroll
  for(int it = 0; it < 12; ++it){
    int item = it*256 + t;
    int d = item % DI, pl = item / DI;
    float v = (ym[pl][d] - mu[pl]) * rs[pl];
    ym[pl][d] = v * ld1<BF>(gamma, d) + ld1<BF>(beta, d);
  }
  __syncthreads();
  {
    int pl = t & 15, cg = t >> 4;   // 16 c-groups of 12
    float acc[12];
    #pragma unroll
    for(int j = 0; j < 12; ++j) acc[j] = 0.f;
    for(int dd = 0; dd < DI; ++dd){
      float v = ym[pl][dd];
      size_t wrow = (size_t)dd*DI + cg*12;
      float4 w0 = ld4<BF>(Wout, wrow), w1 = ld4<BF>(Wout, wrow+4), w2 = ld4<BF>(Wout, wrow+8);
      acc[0]  += v*w0.x; acc[1]  += v*w0.y; acc[2]  += v*w0.z; acc[3]  += v*w0.w;
      acc[4]  += v*w1.x; acc[5]  += v*w1.y; acc[6]  += v*w1.z; acc[7]  += v*w1.w;
      acc[8]  += v*w2.x; acc[9]  += v*w2.y; acc[10] += v*w2.z; acc[11] += v*w2.w;
    }
    #pragma unroll
    for(int j = 0; j < 12; ++j){
      int c = cg*12 + j;
      stout<BF>(Out, ((size_t)b*DI + c)*LLEN + l0 + pl, acc[j]);
    }
  }
}
__global__ __launch_bounds__(256) void k_post(const float* Acc, const void* gamma,
                                              const void* beta, const void* Wout,
                                              void* Out, const uint32* flag){
  __shared__ float ym[16][204];
  __shared__ float mu[16], rs[16];
  if(*flag) post_impl<true>(Acc, gamma, beta, Wout, Out, ym, mu, rs);
  else      post_impl<false>(Acc, gamma, beta, Wout, Out, ym, mu, rs);
}

extern "C" void kernel_launch(void* const* d_in, const int* in_sizes, int n_in,
                              void* d_out, int out_size, void* d_ws, size_t ws_size,
                              hipStream_t stream){
  (void)in_sizes; (void)n_in; (void)out_size; (void)ws_size;
  const void* x    = d_in[0];
  const void* y    = d_in[1];
  const void* wx   = d_in[2];
  const void* wy   = d_in[3];
  const void* xpw  = d_in[4];
  const void* wdt  = d_in[5];
  const void* dtb  = d_in[6];
  const void* alog = d_in[7];
  const void* dsv  = d_in[8];
  const void* gam  = d_in[9];
  const void* bet  = d_in[10];
  const void* wout = d_in[11];

  float* ws   = (float*)d_ws;
  uint32* flag = (uint32*)ws;                                  // 16-float pad
  float* xin  = ws + 16;                                       // BLD
  float* yin  = xin  + BLD;                                    // BLD
  float* dtsP = yin  + BLD;                                    // B*K*L*12
  float* bc   = dtsP + (size_t)BATCH*KKDIR*LLEN*RK;            // B*K*L*32
  float* acc  = bc   + (size_t)BATCH*KKDIR*LLEN*32;            // BLD
  float* sarr = acc  + BLD;                                    // B*K*D*NCH*NS
  float* parr = sarr + (size_t)BATCH*KKDIR*DI*NCH*NS;          // B*K*D*NCH*NS
  // total: 16 + 3*BLD + 0.786M + 2.097M + 2*3.146M floats ~= 74.5 MB

  k_detect<<<1, 64, 0, stream>>>(alog, flag);
  hipMemsetAsync(acc, 0, BLD*sizeof(float), stream);
  k_inproj<<<256, 256, 0, stream>>>(x, wx, xin, flag);
  k_inproj<<<256, 256, 0, stream>>>(y, wy, yin, flag);
  k_proj<<<1024, 256, 0, stream>>>(xin, xpw, dtsP, bc, flag);
  k_scan1<<<BATCH*KKDIR*NCH, 384, 0, stream>>>(dtsP, yin, bc, alog, wdt, dtb, sarr, parr, flag);
  k_scan2<<<192, 256, 0, stream>>>(sarr, parr);
  k_scan3<<<BATCH*KKDIR*NCH, 384, 0, stream>>>(dtsP, yin, bc, alog, wdt, dtb, dsv, sarr, acc, flag);
  k_post<<<1024, 256, 0, stream>>>(acc, gam, bet, wout, d_out, flag);
}

// Round 4
// 390.425 us; speedup vs baseline: 1.3948x; 1.0931x over previous
//
#include <hip/hip_runtime.h>

typedef unsigned int uint32;
typedef unsigned short ushort_t;

#define BATCH 4
#define DI    192   // d_inner == d_model
#define KKDIR 4
#define NS    16    // d_state
#define RK    12    // dt_rank
#define LLEN  4096  // H*W
#define CDBL  44    // RK + 2*NS
#define NCH   64    // scan chunks
#define CLEN  64    // chunk length
#define BLD   ((size_t)BATCH*LLEN*DI)
#define YPAD  205   // 205%32=13 -> GEMM-phase LDS reads land 2/bank (free)

__device__ __forceinline__ float bf2f(ushort_t u){
  union { uint32 i; float f; } v; v.i = ((uint32)u) << 16; return v.f;
}
__device__ __forceinline__ ushort_t f2bf(float f){
  union { float f; uint32 i; } v; v.f = f;
  return (ushort_t)((v.i + 0x7fffu + ((v.i >> 16) & 1u)) >> 16);
}
// dual-dtype loads: BF=true -> packed bf16, BF=false -> fp32
template<bool BF> __device__ __forceinline__ float ld1(const void* p, size_t i){
  if(BF) return bf2f(((const ushort_t*)p)[i]);
  return ((const float*)p)[i];
}
template<bool BF> __device__ __forceinline__ float2 ld2(const void* p, size_t i){
  if(BF){
    uint32 w = *(const uint32*)(((const ushort_t*)p) + i);
    return make_float2(bf2f((ushort_t)(w & 0xffffu)), bf2f((ushort_t)(w >> 16)));
  }
  return *(const float2*)(((const float*)p) + i);
}
template<bool BF> __device__ __forceinline__ float4 ld4(const void* p, size_t i){
  if(BF){
    uint2 w = *(const uint2*)(((const ushort_t*)p) + i);
    return make_float4(bf2f((ushort_t)(w.x & 0xffffu)), bf2f((ushort_t)(w.x >> 16)),
                       bf2f((ushort_t)(w.y & 0xffffu)), bf2f((ushort_t)(w.y >> 16)));
  }
  return *(const float4*)(((const float*)p) + i);
}
struct __attribute__((aligned(8))) us4 { ushort_t x, y, z, w; };
template<bool BF> __device__ __forceinline__ void st4(void* p, size_t i,
                                                      float a, float b, float c, float d){
  if(BF){
    us4 v; v.x = f2bf(a); v.y = f2bf(b); v.z = f2bf(c); v.w = f2bf(d);
    *(us4*)(((ushort_t*)p) + i) = v;
  } else {
    *(float4*)(((float*)p) + i) = make_float4(a, b, c, d);
  }
}
// direction k: sequence position l maps to spatial p = p0(k,l0) + ps(k)*j within an
// aligned 64-chunk (l0 = ch*CLEN, CLEN=64). permk is an involution.
__device__ __forceinline__ int perm_p0(int k, int l0){
  if(k == 0) return l0;
  if(k == 1) return l0 >> 6;
  if(k == 2) return 4095 - l0;
  return 4095 - (l0 >> 6);
}
__device__ __forceinline__ int perm_ps(int k){
  if(k == 0) return 1;
  if(k == 1) return 64;
  if(k == 2) return -1;
  return -64;
}
__device__ __forceinline__ float softplusf(float a){
  return fmaxf(a, 0.f) + __logf(1.f + __expf(-fabsf(a)));
}

// ---------------- K0: dtype detect (A_logs[0]==log(1)==0.0f iff fp32) ----------------
__global__ void k_detect(const void* alog, uint32* flag){
  if(threadIdx.x == 0 && blockIdx.x == 0)
    *flag = (*(const uint32*)alog != 0u) ? 1u : 0u;
}

// ---------------- K1: input projection  Xout[b,l,d] = sum_c X[b,c,l]*W[c,d] ----------------
template<bool BF>
__device__ void inproj_impl(const void* X, const void* Wm, float* Xout, float (*xs)[64]){
  const int b  = blockIdx.x >> 6;
  const int l0 = (blockIdx.x & 63) << 6;
  const int t  = threadIdx.x;
  for(int idx = t; idx < DI*64; idx += 256){
    int c = idx >> 6, lc = idx & 63;
    xs[c][lc] = ld1<BF>(X, (size_t)(b*DI + c)*LLEN + l0 + lc);
  }
  __syncthreads();
  #pragma unroll
  for(int it = 0; it < 3; ++it){
    int item = it*256 + t;      // 48 d-groups x 16 l-groups
    int dg = item % 48;
    int lg = item / 48;
    float a00=0,a01=0,a02=0,a03=0,a10=0,a11=0,a12=0,a13=0;
    float a20=0,a21=0,a22=0,a23=0,a30=0,a31=0,a32=0,a33=0;
    #pragma unroll 4
    for(int c = 0; c < DI; ++c){
      float4 w = ld4<BF>(Wm, (size_t)c*DI + dg*4);
      float4 xv = *(const float4*)&xs[c][lg*4];
      a00 += xv.x*w.x; a01 += xv.x*w.y; a02 += xv.x*w.z; a03 += xv.x*w.w;
      a10 += xv.y*w.x; a11 += xv.y*w.y; a12 += xv.y*w.z; a13 += xv.y*w.w;
      a20 += xv.z*w.x; a21 += xv.z*w.y; a22 += xv.z*w.z; a23 += xv.z*w.w;
      a30 += xv.w*w.x; a31 += xv.w*w.y; a32 += xv.w*w.z; a33 += xv.w*w.w;
    }
    size_t rb = ((size_t)b*LLEN + l0 + lg*4)*DI + dg*4;
    *(float4*)(Xout + rb)        = make_float4(a00,a01,a02,a03);
    *(float4*)(Xout + rb + DI)   = make_float4(a10,a11,a12,a13);
    *(float4*)(Xout + rb + 2*DI) = make_float4(a20,a21,a22,a23);
    *(float4*)(Xout + rb + 3*DI) = make_float4(a30,a31,a32,a33);
  }
}
__global__ __launch_bounds__(256) void k_inproj(const void* X, const void* Wm,
                                                float* Xout, const uint32* flag){
  __shared__ float xs[DI][64];
  if(*flag) inproj_impl<true>(X, Wm, Xout, xs);
  else      inproj_impl<false>(X, Wm, Xout, xs);
}

// ---------------- K2: per-location direction projections -> dtsP, B/C ----------------
template<bool BF>
__device__ void proj_impl(const float* Xin, const void* Wp,
                          float* dtsP, float* BC,
                          float (*xr)[204], float (*Pl)[17]){
  const int b  = blockIdx.x >> 8;
  const int p0 = (blockIdx.x & 255) << 4;
  const int t  = threadIdx.x;
  for(int idx = t; idx < 16*DI; idx += 256){
    int pl = idx / DI, d = idx % DI;
    xr[pl][d] = Xin[((size_t)b*LLEN + p0 + pl)*DI + d];
  }
  __syncthreads();
  // P[k][c][pl] = dot(x_row, Wp[k][c][:]) : 4*44*16 = 2816 items
  #pragma unroll
  for(int it = 0; it < 11; ++it){
    int item = it*256 + t;
    int pl = item & 15;
    int kc = item >> 4;
    float acc = 0.f;
    #pragma unroll 4
    for(int j = 0; j < DI/4; ++j){
      float4 w = ld4<BF>(Wp, (size_t)kc*DI + j*4);
      float4 xv = *(const float4*)&xr[pl][j*4];
      acc += xv.x*w.x + xv.y*w.y + xv.z*w.z + xv.w*w.w;
    }
    Pl[kc][pl] = acc;
  }
  __syncthreads();
  // store dts rows: 16 pl x 4 k x 12 r = 768
  {
    int item = t;
    for(int it = 0; it < 3; ++it, item += 256){
      int pl  = item / 48;
      int rem = item % 48;
      int k = rem / RK, r = rem % RK;
      dtsP[(((size_t)b*KKDIR + k)*LLEN + p0 + pl)*RK + r] = Pl[k*CDBL + r][pl];
    }
  }
  // store B/C: 16 pl x 4 k x 32 c = 2048
  #pragma unroll
  for(int it = 0; it < 8; ++it){
    int item = it*256 + t;
    int pl  = item >> 7;
    int rem = item & 127;
    int k = rem >> 5, c2 = rem & 31;
    BC[(((size_t)b*KKDIR + k)*LLEN + p0 + pl)*32 + c2] = Pl[k*CDBL + 12 + c2][pl];
  }
}
__global__ __launch_bounds__(256) void k_proj(const float* Xin, const void* Wp,
                                              float* dtsP, float* BC, const uint32* flag){
  __shared__ float xr[16][204];
  __shared__ float Pl[KKDIR*CDBL][17];
  if(*flag) proj_impl<true>(Xin, Wp, dtsP, BC, xr, Pl);
  else      proj_impl<false>(Xin, Wp, dtsP, BC, xr, Pl);
}

// ---------------- K3a: chunked scan phase 1; n-split-2 (thread = d*2+nh, 8 states) ----------
template<bool BF>
__device__ void scan1_impl(const float* dtsP, const float* Yin, const float* BC,
                           const void* Alog, const void* Wdt, const void* biasw,
                           float* Sarr, float* Parr,
                           float (*bs)[NS], float (*pr)[RK]){
  const int blk = blockIdx.x;
  const int ch = blk % NCH;
  const int bk = blk / NCH;   // b*K + k
  const int k  = bk % KKDIR;
  const int b  = bk / KKDIR;
  const int t  = threadIdx.x;
  const int d  = t >> 1;
  const int nh = t & 1;       // which 8-state half
  const int l0 = ch * CLEN;
  const int p0 = perm_p0(k, l0);
  const int ps = perm_ps(k);
  for(int idx = t; idx < CLEN*NS; idx += 384){
    int j = idx >> 4, n = idx & 15;
    bs[j][n] = BC[((size_t)bk*LLEN + p0 + ps*j)*32 + n];
  }
  for(int idx = t; idx < CLEN*RK; idx += 384){
    int j = idx / RK, r = idx - j*RK;
    pr[j][r] = dtsP[((size_t)bk*LLEN + p0 + ps*j)*RK + r];
  }
  float as2[8];
  {
    size_t arow = (size_t)(k*DI + d)*NS + nh*8;
    #pragma unroll
    for(int n = 0; n < 8; ++n) as2[n] = -__expf(ld1<BF>(Alog, arow + n)) * 1.44269504f;
  }
  float wv[RK];
  {
    size_t wrow = (size_t)(k*DI + d)*RK;
    float4 w0 = ld4<BF>(Wdt, wrow), w1 = ld4<BF>(Wdt, wrow+4), w2 = ld4<BF>(Wdt, wrow+8);
    wv[0]=w0.x; wv[1]=w0.y; wv[2]=w0.z; wv[3]=w0.w;
    wv[4]=w1.x; wv[5]=w1.y; wv[6]=w1.z; wv[7]=w1.w;
    wv[8]=w2.x; wv[9]=w2.y; wv[10]=w2.z; wv[11]=w2.w;
  }
  const float bv = ld1<BF>(biasw, k*DI + d);
  float h[8];
  #pragma unroll
  for(int n = 0; n < 8; ++n) h[n] = 0.f;
  float sdt = 0.f;
  __syncthreads();
  const float* yrow = Yin + (size_t)b*LLEN*DI + d;
  int p = p0;
  #pragma unroll 2
  for(int j = 0; j < CLEN; ++j){
    float4 q0 = *(const float4*)&pr[j][0];
    float4 q1 = *(const float4*)&pr[j][4];
    float4 q2 = *(const float4*)&pr[j][8];
    float a = bv + q0.x*wv[0] + q0.y*wv[1] + q0.z*wv[2] + q0.w*wv[3]
                 + q1.x*wv[4] + q1.y*wv[5] + q1.z*wv[6] + q1.w*wv[7]
                 + q2.x*wv[8] + q2.y*wv[9] + q2.z*wv[10] + q2.w*wv[11];
    float dt = softplusf(a);
    float u  = yrow[(size_t)p*DI];
    sdt += dt;
    float dtu = dt*u;
    float4 b0 = *(const float4*)&bs[j][nh*8];
    float4 b1 = *(const float4*)&bs[j][nh*8+4];
    h[0] = __builtin_amdgcn_exp2f(dt*as2[0])*h[0] + dtu*b0.x;
    h[1] = __builtin_amdgcn_exp2f(dt*as2[1])*h[1] + dtu*b0.y;
    h[2] = __builtin_amdgcn_exp2f(dt*as2[2])*h[2] + dtu*b0.z;
    h[3] = __builtin_amdgcn_exp2f(dt*as2[3])*h[3] + dtu*b0.w;
    h[4] = __builtin_amdgcn_exp2f(dt*as2[4])*h[4] + dtu*b1.x;
    h[5] = __builtin_amdgcn_exp2f(dt*as2[5])*h[5] + dtu*b1.y;
    h[6] = __builtin_amdgcn_exp2f(dt*as2[6])*h[6] + dtu*b1.z;
    h[7] = __builtin_amdgcn_exp2f(dt*as2[7])*h[7] + dtu*b1.w;
    p += ps;
  }
  size_t base = ((size_t)(bk*DI + d)*NCH + ch)*NS + nh*8;
  *(float4*)(Sarr+base)   = make_float4(h[0],h[1],h[2],h[3]);
  *(float4*)(Sarr+base+4) = make_float4(h[4],h[5],h[6],h[7]);
  float pv[8];
  #pragma unroll
  for(int n = 0; n < 8; ++n) pv[n] = __builtin_amdgcn_exp2f(as2[n]*sdt);
  *(float4*)(Parr+base)   = make_float4(pv[0],pv[1],pv[2],pv[3]);
  *(float4*)(Parr+base+4) = make_float4(pv[4],pv[5],pv[6],pv[7]);
}
__global__ __launch_bounds__(384) void k_scan1(const float* dtsP, const float* Yin,
                                               const float* BC, const void* Alog,
                                               const void* Wdt, const void* biasw,
                                               float* Sarr, float* Parr, const uint32* flag){
  __shared__ float bs[CLEN][NS];
  __shared__ float pr[CLEN][RK];
  if(*flag) scan1_impl<true>(dtsP, Yin, BC, Alog, Wdt, biasw, Sarr, Parr, bs, pr);
  else      scan1_impl<false>(dtsP, Yin, BC, Alog, Wdt, biasw, Sarr, Parr, bs, pr);
}

// ---------------- K3b: cross-chunk prefix (in-place: Sarr becomes h_in per chunk) -------------
__global__ __launch_bounds__(256) void k_scan2(float* __restrict__ Sarr,
                                               const float* __restrict__ Parr){
  int tid = blockIdx.x*256 + threadIdx.x;   // 49152 = B*K*D*N
  int n = tid & 15;
  int bkd = tid >> 4;
  float h = 0.f;
  for(int c = 0; c < NCH; ++c){
    size_t i = ((size_t)bkd*NCH + c)*NS + n;
    float s = Sarr[i], p = Parr[i];
    Sarr[i] = h;
    h = p*h + s;
  }
}

// ---------------- K3c: scan phase 3; n-split-2; atomic-accumulate y at spatial pos -----------
template<bool BF>
__device__ void scan3_impl(const float* dtsP, const float* Yin, const float* BC,
                           const void* Alog, const void* Wdt, const void* biasw,
                           const void* DsI, const float* Hin, float* Acc,
                           float (*bs)[32], float (*pr)[RK]){
  const int blk = blockIdx.x;
  const int ch = blk % NCH;
  const int bk = blk / NCH;
  const int k  = bk % KKDIR;
  const int b  = bk / KKDIR;
  const int t  = threadIdx.x;
  const int d  = t >> 1;
  const int nh = t & 1;
  const int l0 = ch * CLEN;
  const int p0 = perm_p0(k, l0);
  const int ps = perm_ps(k);
  for(int idx = t; idx < CLEN*32; idx += 384){
    int j = idx >> 5, n = idx & 31;
    bs[j][n] = BC[((size_t)bk*LLEN + p0 + ps*j)*32 + n];
  }
  for(int idx = t; idx < CLEN*RK; idx += 384){
    int j = idx / RK, r = idx - j*RK;
    pr[j][r] = dtsP[((size_t)bk*LLEN + p0 + ps*j)*RK + r];
  }
  float as2[8];
  {
    size_t arow = (size_t)(k*DI + d)*NS + nh*8;
    #pragma unroll
    for(int n = 0; n < 8; ++n) as2[n] = -__expf(ld1<BF>(Alog, arow + n)) * 1.44269504f;
  }
  float wv[RK];
  {
    size_t wrow = (size_t)(k*DI + d)*RK;
    float4 w0 = ld4<BF>(Wdt, wrow), w1 = ld4<BF>(Wdt, wrow+4), w2 = ld4<BF>(Wdt, wrow+8);
    wv[0]=w0.x; wv[1]=w0.y; wv[2]=w0.z; wv[3]=w0.w;
    wv[4]=w1.x; wv[5]=w1.y; wv[6]=w1.z; wv[7]=w1.w;
    wv[8]=w2.x; wv[9]=w2.y; wv[10]=w2.z; wv[11]=w2.w;
  }
  const float bv = ld1<BF>(biasw, k*DI + d);
  const float dsv = ld1<BF>(DsI, k*DI + d);
  float h[8];
  {
    size_t hbase = ((size_t)(bk*DI + d)*NCH + ch)*NS + nh*8;
    float4 h0 = *(const float4*)(Hin + hbase);
    float4 h1 = *(const float4*)(Hin + hbase + 4);
    h[0]=h0.x; h[1]=h0.y; h[2]=h0.z; h[3]=h0.w;
    h[4]=h1.x; h[5]=h1.y; h[6]=h1.z; h[7]=h1.w;
  }
  __syncthreads();
  const float* yrow = Yin + (size_t)b*LLEN*DI + d;
  float* arow = Acc + (size_t)b*LLEN*DI + d;
  int p = p0;
  #pragma unroll 2
  for(int j = 0; j < CLEN; ++j){
    float4 q0 = *(const float4*)&pr[j][0];
    float4 q1 = *(const float4*)&pr[j][4];
    float4 q2 = *(const float4*)&pr[j][8];
    float a = bv + q0.x*wv[0] + q0.y*wv[1] + q0.z*wv[2] + q0.w*wv[3]
                 + q1.x*wv[4] + q1.y*wv[5] + q1.z*wv[6] + q1.w*wv[7]
                 + q2.x*wv[8] + q2.y*wv[9] + q2.z*wv[10] + q2.w*wv[11];
    float dt = softplusf(a);
    float u  = yrow[(size_t)p*DI];
    float dtu = dt*u;
    float4 b0 = *(const float4*)&bs[j][nh*8];
    float4 b1 = *(const float4*)&bs[j][nh*8+4];
    float4 c0 = *(const float4*)&bs[j][16+nh*8];
    float4 c1 = *(const float4*)&bs[j][16+nh*8+4];
    float y = (nh == 0) ? dsv*u : 0.f;
    h[0] = __builtin_amdgcn_exp2f(dt*as2[0])*h[0] + dtu*b0.x;  y += h[0]*c0.x;
    h[1] = __builtin_amdgcn_exp2f(dt*as2[1])*h[1] + dtu*b0.y;  y += h[1]*c0.y;
    h[2] = __builtin_amdgcn_exp2f(dt*as2[2])*h[2] + dtu*b0.z;  y += h[2]*c0.z;
    h[3] = __builtin_amdgcn_exp2f(dt*as2[3])*h[3] + dtu*b0.w;  y += h[3]*c0.w;
    h[4] = __builtin_amdgcn_exp2f(dt*as2[4])*h[4] + dtu*b1.x;  y += h[4]*c1.x;
    h[5] = __builtin_amdgcn_exp2f(dt*as2[5])*h[5] + dtu*b1.y;  y += h[5]*c1.y;
    h[6] = __builtin_amdgcn_exp2f(dt*as2[6])*h[6] + dtu*b1.z;  y += h[6]*c1.z;
    h[7] = __builtin_amdgcn_exp2f(dt*as2[7])*h[7] + dtu*b1.w;  y += h[7]*c1.w;
    y += __shfl_xor(y, 1);
    if(nh == 0) atomicAdd(arow + (size_t)p*DI, y);  // involution: seq l emits at spatial p
    p += ps;
  }
}
__global__ __launch_bounds__(384) void k_scan3(const float* dtsP, const float* Yin,
                                               const float* BC, const void* Alog,
                                               const void* Wdt, const void* biasw,
                                               const void* DsI, const float* Hin,
                                               float* Acc, const uint32* flag){
  __shared__ float bs[CLEN][32];
  __shared__ float pr[CLEN][RK];
  if(*flag) scan3_impl<true>(dtsP, Yin, BC, Alog, Wdt, biasw, DsI, Hin, Acc, bs, pr);
  else      scan3_impl<false>(dtsP, Yin, BC, Alog, Wdt, biasw, DsI, Hin, Acc, bs, pr);
}

// ---------------- K4: LayerNorm + out_proj + store (64 rows x 96 cols per block) ----------
// grid 512: b = blk>>7, lblk = (blk>>1)&63, chalf = blk&1. 2 blocks/CU (52KB LDS).
template<bool BF>
__device__ void post_impl(const float* Acc, const void* gamma, const void* beta,
                          const void* Wout, void* Out,
                          float (*ym)[YPAD], float* mu, float* rs,
                          float* gs, float* bt){
  const int b     = blockIdx.x >> 7;
  const int l0    = ((blockIdx.x >> 1) & 63) << 6;
  const int chalf = blockIdx.x & 1;
  const int t     = threadIdx.x;
  // stage gamma/beta
  if(t < DI){ gs[t] = ld1<BF>(gamma, t); bt[t] = ld1<BF>(beta, t); }
  // A: load 64x192 rows
  for(int idx = t; idx < 64*48; idx += 256){
    int l = idx / 48, d4 = (idx % 48) * 4;
    float4 v = *(const float4*)(Acc + ((size_t)b*LLEN + l0 + l)*DI + d4);
    ym[l][d4] = v.x; ym[l][d4+1] = v.y; ym[l][d4+2] = v.z; ym[l][d4+3] = v.w;
  }
  __syncthreads();
  // B: LN stats (4 threads per row)
  const int row = t >> 2, sub = t & 3;
  {
    float s1 = 0.f, s2 = 0.f;
    #pragma unroll 8
    for(int j = 0; j < 48; ++j){
      float v = ym[row][sub*48 + j];
      s1 += v; s2 += v*v;
    }
    s1 += __shfl_xor(s1, 1); s2 += __shfl_xor(s2, 1);
    s1 += __shfl_xor(s1, 2); s2 += __shfl_xor(s2, 2);
    if(sub == 0){
      float mean = s1 * (1.f/192.f);
      float var  = s2 * (1.f/192.f) - mean*mean;
      mu[row] = mean;
      rs[row] = rsqrtf(var + 1e-5f);
    }
  }
  __syncthreads();
  // C: normalize + affine in-place
  {
    float m = mu[row], r = rs[row];
    #pragma unroll 8
    for(int j = 0; j < 48; ++j){
      int d = sub*48 + j;
      ym[row][d] = (ym[row][d] - m) * r * gs[d] + bt[d];
    }
  }
  __syncthreads();
  // D: GEMM 64l x 96c: thread = (lg = t&15 -> 4 l, cg = t>>4 -> 6 c)
  {
    const int lg = t & 15, cg = t >> 4;
    const int c0 = chalf*96 + cg*6;
    float acc[24];
    #pragma unroll
    for(int i = 0; i < 24; ++i) acc[i] = 0.f;
    for(int dd = 0; dd < DI; ++dd){
      float x0 = ym[lg*4+0][dd];
      float x1 = ym[lg*4+1][dd];
      float x2 = ym[lg*4+2][dd];
      float x3 = ym[lg*4+3][dd];
      size_t wrow = (size_t)dd*DI + c0;
      float4 wA = ld4<BF>(Wout, wrow);
      float2 wB = ld2<BF>(Wout, wrow + 4);
      float w[6] = {wA.x, wA.y, wA.z, wA.w, wB.x, wB.y};
      #pragma unroll
      for(int jc = 0; jc < 6; ++jc){
        acc[jc*4+0] += x0*w[jc];
        acc[jc*4+1] += x1*w[jc];
        acc[jc*4+2] += x2*w[jc];
        acc[jc*4+3] += x3*w[jc];
      }
    }
    #pragma unroll
    for(int jc = 0; jc < 6; ++jc){
      int c = c0 + jc;
      st4<BF>(Out, ((size_t)b*DI + c)*LLEN + l0 + lg*4,
              acc[jc*4+0], acc[jc*4+1], acc[jc*4+2], acc[jc*4+3]);
    }
  }
}
__global__ __launch_bounds__(256) void k_post(const float* Acc, const void* gamma,
                                              const void* beta, const void* Wout,
                                              void* Out, const uint32* flag){
  __shared__ float ym[64][YPAD];
  __shared__ float mu[64], rs[64];
  __shared__ float gs[DI], bt[DI];
  if(*flag) post_impl<true>(Acc, gamma, beta, Wout, Out, ym, mu, rs, gs, bt);
  else      post_impl<false>(Acc, gamma, beta, Wout, Out, ym, mu, rs, gs, bt);
}

extern "C" void kernel_launch(void* const* d_in, const int* in_sizes, int n_in,
                              void* d_out, int out_size, void* d_ws, size_t ws_size,
                              hipStream_t stream){
  (void)in_sizes; (void)n_in; (void)out_size; (void)ws_size;
  const void* x    = d_in[0];
  const void* y    = d_in[1];
  const void* wx   = d_in[2];
  const void* wy   = d_in[3];
  const void* xpw  = d_in[4];
  const void* wdt  = d_in[5];
  const void* dtb  = d_in[6];
  const void* alog = d_in[7];
  const void* dsv  = d_in[8];
  const void* gam  = d_in[9];
  const void* bet  = d_in[10];
  const void* wout = d_in[11];

  float* ws   = (float*)d_ws;
  uint32* flag = (uint32*)ws;                                  // 16-float pad
  float* xin  = ws + 16;                                       // BLD
  float* yin  = xin  + BLD;                                    // BLD
  float* dtsP = yin  + BLD;                                    // B*K*L*12
  float* bc   = dtsP + (size_t)BATCH*KKDIR*LLEN*RK;            // B*K*L*32
  float* acc  = bc   + (size_t)BATCH*KKDIR*LLEN*32;            // BLD
  float* sarr = acc  + BLD;                                    // B*K*D*NCH*NS
  float* parr = sarr + (size_t)BATCH*KKDIR*DI*NCH*NS;          // B*K*D*NCH*NS
  // total: 16 + 3*BLD + 0.786M + 2.097M + 2*3.146M floats ~= 74.5 MB

  k_detect<<<1, 64, 0, stream>>>(alog, flag);
  hipMemsetAsync(acc, 0, BLD*sizeof(float), stream);
  k_inproj<<<256, 256, 0, stream>>>(x, wx, xin, flag);
  k_inproj<<<256, 256, 0, stream>>>(y, wy, yin, flag);
  k_proj<<<1024, 256, 0, stream>>>(xin, xpw, dtsP, bc, flag);
  k_scan1<<<BATCH*KKDIR*NCH, 384, 0, stream>>>(dtsP, yin, bc, alog, wdt, dtb, sarr, parr, flag);
  k_scan2<<<192, 256, 0, stream>>>(sarr, parr);
  k_scan3<<<BATCH*KKDIR*NCH, 384, 0, stream>>>(dtsP, yin, bc, alog, wdt, dtb, dsv, sarr, acc, flag);
  k_post<<<BATCH*64*2, 256, 0, stream>>>(acc, gam, bet, wout, d_out, flag);
}

// Round 5
// 363.048 us; speedup vs baseline: 1.5000x; 1.0754x over previous
//
#include <hip/hip_runtime.h>

typedef unsigned int uint32;
typedef unsigned short ushort_t;

#define BATCH 4
#define DI    192   // d_inner == d_model
#define KKDIR 4
#define NS    16    // d_state
#define RK    12    // dt_rank
#define LLEN  4096  // H*W
#define CDBL  44    // RK + 2*NS
#define NCH   64    // scan chunks
#define CLEN  64    // chunk length
#define BLD   ((size_t)BATCH*LLEN*DI)
#define YPAD  205   // 205%32=13 -> GEMM-phase LDS reads land 2/bank (free)

__device__ __forceinline__ float bf2f(ushort_t u){
  union { uint32 i; float f; } v; v.i = ((uint32)u) << 16; return v.f;
}
__device__ __forceinline__ ushort_t f2bf(float f){
  union { float f; uint32 i; } v; v.f = f;
  return (ushort_t)((v.i + 0x7fffu + ((v.i >> 16) & 1u)) >> 16);
}
// dual-dtype loads: BF=true -> packed bf16, BF=false -> fp32
template<bool BF> __device__ __forceinline__ float ld1(const void* p, size_t i){
  if(BF) return bf2f(((const ushort_t*)p)[i]);
  return ((const float*)p)[i];
}
template<bool BF> __device__ __forceinline__ float2 ld2(const void* p, size_t i){
  if(BF){
    uint32 w = *(const uint32*)(((const ushort_t*)p) + i);
    return make_float2(bf2f((ushort_t)(w & 0xffffu)), bf2f((ushort_t)(w >> 16)));
  }
  return *(const float2*)(((const float*)p) + i);
}
template<bool BF> __device__ __forceinline__ float4 ld4(const void* p, size_t i){
  if(BF){
    uint2 w = *(const uint2*)(((const ushort_t*)p) + i);
    return make_float4(bf2f((ushort_t)(w.x & 0xffffu)), bf2f((ushort_t)(w.x >> 16)),
                       bf2f((ushort_t)(w.y & 0xffffu)), bf2f((ushort_t)(w.y >> 16)));
  }
  return *(const float4*)(((const float*)p) + i);
}
struct __attribute__((aligned(8))) us4 { ushort_t x, y, z, w; };
template<bool BF> __device__ __forceinline__ void st4(void* p, size_t i,
                                                      float a, float b, float c, float d){
  if(BF){
    us4 v; v.x = f2bf(a); v.y = f2bf(b); v.z = f2bf(c); v.w = f2bf(d);
    *(us4*)(((ushort_t*)p) + i) = v;
  } else {
    *(float4*)(((float*)p) + i) = make_float4(a, b, c, d);
  }
}
// direction k: sequence position l maps to spatial p = p0(k,l0) + ps(k)*j within an
// aligned 64-chunk (l0 = ch*CLEN, CLEN=64). permk is an involution.
__device__ __forceinline__ int perm_p0(int k, int l0){
  if(k == 0) return l0;
  if(k == 1) return l0 >> 6;
  if(k == 2) return 4095 - l0;
  return 4095 - (l0 >> 6);
}
__device__ __forceinline__ int perm_ps(int k){
  if(k == 0) return 1;
  if(k == 1) return 64;
  if(k == 2) return -1;
  return -64;
}
__device__ __forceinline__ float softplusf(float a){
  return fmaxf(a, 0.f) + __logf(1.f + __expf(-fabsf(a)));
}

// ---------------- K0: dtype detect (A_logs[0]==log(1)==0.0f iff fp32) ----------------
__global__ void k_detect(const void* alog, uint32* flag){
  if(threadIdx.x == 0 && blockIdx.x == 0)
    *flag = (*(const uint32*)alog != 0u) ? 1u : 0u;
}

// ---------------- K1: input projection  Xout[b,l,d] = sum_c X[b,c,l]*W[c,d] ----------------
template<bool BF>
__device__ void inproj_impl(const void* X, const void* Wm, float* Xout, float (*xs)[64]){
  const int b  = blockIdx.x >> 6;
  const int l0 = (blockIdx.x & 63) << 6;
  const int t  = threadIdx.x;
  for(int idx = t; idx < DI*64; idx += 256){
    int c = idx >> 6, lc = idx & 63;
    xs[c][lc] = ld1<BF>(X, (size_t)(b*DI + c)*LLEN + l0 + lc);
  }
  __syncthreads();
  #pragma unroll
  for(int it = 0; it < 3; ++it){
    int item = it*256 + t;      // 48 d-groups x 16 l-groups
    int dg = item % 48;
    int lg = item / 48;
    float a00=0,a01=0,a02=0,a03=0,a10=0,a11=0,a12=0,a13=0;
    float a20=0,a21=0,a22=0,a23=0,a30=0,a31=0,a32=0,a33=0;
    #pragma unroll 4
    for(int c = 0; c < DI; ++c){
      float4 w = ld4<BF>(Wm, (size_t)c*DI + dg*4);
      float4 xv = *(const float4*)&xs[c][lg*4];
      a00 += xv.x*w.x; a01 += xv.x*w.y; a02 += xv.x*w.z; a03 += xv.x*w.w;
      a10 += xv.y*w.x; a11 += xv.y*w.y; a12 += xv.y*w.z; a13 += xv.y*w.w;
      a20 += xv.z*w.x; a21 += xv.z*w.y; a22 += xv.z*w.z; a23 += xv.z*w.w;
      a30 += xv.w*w.x; a31 += xv.w*w.y; a32 += xv.w*w.z; a33 += xv.w*w.w;
    }
    size_t rb = ((size_t)b*LLEN + l0 + lg*4)*DI + dg*4;
    *(float4*)(Xout + rb)        = make_float4(a00,a01,a02,a03);
    *(float4*)(Xout + rb + DI)   = make_float4(a10,a11,a12,a13);
    *(float4*)(Xout + rb + 2*DI) = make_float4(a20,a21,a22,a23);
    *(float4*)(Xout + rb + 3*DI) = make_float4(a30,a31,a32,a33);
  }
}
__global__ __launch_bounds__(256) void k_inproj(const void* X, const void* Wm,
                                                float* Xout, const uint32* flag){
  __shared__ float xs[DI][64];
  if(*flag) inproj_impl<true>(X, Wm, Xout, xs);
  else      inproj_impl<false>(X, Wm, Xout, xs);
}

// ---------------- K2: direction projections as K-tiled GEMM -> dtsP, B/C ----------------
// C[64 pl x 96 cpad] per block; cpad = k*48 + j (j<12 dts, 12<=j<44 B/C, j>=44 pad).
// grid 512: b = blk>>7, lb = (blk>>1)&63, chalf = blk&1.
template<bool BF>
__device__ void proj_impl(const float* Xin, const void* Wp,
                          float* dtsP, float* BC,
                          float (*xs)[68], float (*wsb)[100]){
  const int b     = blockIdx.x >> 7;
  const int lb    = (blockIdx.x >> 1) & 63;
  const int chalf = blockIdx.x & 1;
  const int p0    = lb << 6;
  const int c0    = chalf * 96;
  const int t     = threadIdx.x;
  const int lg    = t & 15;         // 4 pl rows
  const int cg    = t >> 4;         // 6 c cols
  float acc[24];
  #pragma unroll
  for(int i = 0; i < 24; ++i) acc[i] = 0.f;

  for(int kt = 0; kt < 6; ++kt){
    // stage X tile transposed: xs[dd][pl], dd = kt*32..+31
    #pragma unroll
    for(int it = 0; it < 2; ++it){
      int i = it*256 + t;           // 512 items
      int pl = i >> 3, dq = i & 7;
      float4 v = *(const float4*)(Xin + ((size_t)b*LLEN + p0 + pl)*DI + kt*32 + dq*4);
      xs[dq*4+0][pl] = v.x; xs[dq*4+1][pl] = v.y;
      xs[dq*4+2][pl] = v.z; xs[dq*4+3][pl] = v.w;
    }
    // stage W tile unpacked fp32: wsb[dd][cp], cp = 0..95 (global cpad = c0+cp)
    #pragma unroll
    for(int it = 0; it < 6; ++it){
      int i = it*256 + t;           // 1536 items
      int cp = i >> 4, dp = (i & 15) * 2;
      int cpad = c0 + cp;
      int k = cpad / 48, j = cpad % 48;
      float2 v = (j < CDBL) ? ld2<BF>(Wp, (size_t)(k*CDBL + j)*DI + kt*32 + dp)
                            : make_float2(0.f, 0.f);
      wsb[dp][cp] = v.x; wsb[dp+1][cp] = v.y;
    }
    __syncthreads();
    #pragma unroll 4
    for(int dd = 0; dd < 32; ++dd){
      float4 xv = *(const float4*)&xs[dd][lg*4];
      float2 w0 = *(const float2*)&wsb[dd][cg*6];
      float2 w1 = *(const float2*)&wsb[dd][cg*6+2];
      float2 w2 = *(const float2*)&wsb[dd][cg*6+4];
      float w[6] = {w0.x, w0.y, w1.x, w1.y, w2.x, w2.y};
      #pragma unroll
      for(int jc = 0; jc < 6; ++jc){
        acc[0*6+jc] += xv.x*w[jc];
        acc[1*6+jc] += xv.y*w[jc];
        acc[2*6+jc] += xv.z*w[jc];
        acc[3*6+jc] += xv.w*w[jc];
      }
    }
    __syncthreads();
  }
  // epilogue: cpad = c0 + cg*6 + jc; one k per thread (48/6=8 cg-groups per k)
  const int cpad0 = c0 + cg*6;
  const int k  = cpad0 / 48;
  const int j0 = cpad0 % 48;
  #pragma unroll
  for(int pl = 0; pl < 4; ++pl){
    int p = p0 + lg*4 + pl;
    size_t rowbase = ((size_t)(b*KKDIR + k)*LLEN + p);
    #pragma unroll
    for(int jc = 0; jc < 6; ++jc){
      int j = j0 + jc;
      float v = acc[pl*6 + jc];
      if(j < RK)         dtsP[rowbase*RK + j] = v;
      else if(j < CDBL)  BC[rowbase*32 + (j - RK)] = v;
      // j >= 44: pad, discard
    }
  }
}
__global__ __launch_bounds__(256) void k_proj(const float* Xin, const void* Wp,
                                              float* dtsP, float* BC, const uint32* flag){
  __shared__ float xs[32][68];
  __shared__ float wsb[32][100];
  if(*flag) proj_impl<true>(Xin, Wp, dtsP, BC, xs, wsb);
  else      proj_impl<false>(Xin, Wp, dtsP, BC, xs, wsb);
}

// ---------------- K3a: chunked scan phase 1; n-split-2 (thread = d*2+nh, 8 states) ----------
template<bool BF>
__device__ void scan1_impl(const float* dtsP, const float* Yin, const float* BC,
                           const void* Alog, const void* Wdt, const void* biasw,
                           float* Sarr, float* Parr,
                           float (*bs)[NS], float (*pr)[RK]){
  const int blk = blockIdx.x;
  const int ch = blk % NCH;
  const int bk = blk / NCH;   // b*K + k
  const int k  = bk % KKDIR;
  const int b  = bk / KKDIR;
  const int t  = threadIdx.x;
  const int d  = t >> 1;
  const int nh = t & 1;       // which 8-state half
  const int l0 = ch * CLEN;
  const int p0 = perm_p0(k, l0);
  const int ps = perm_ps(k);
  for(int idx = t; idx < CLEN*NS; idx += 384){
    int j = idx >> 4, n = idx & 15;
    bs[j][n] = BC[((size_t)bk*LLEN + p0 + ps*j)*32 + n];
  }
  for(int idx = t; idx < CLEN*RK; idx += 384){
    int j = idx / RK, r = idx - j*RK;
    pr[j][r] = dtsP[((size_t)bk*LLEN + p0 + ps*j)*RK + r];
  }
  float as2[8];
  {
    size_t arow = (size_t)(k*DI + d)*NS + nh*8;
    #pragma unroll
    for(int n = 0; n < 8; ++n) as2[n] = -__expf(ld1<BF>(Alog, arow + n)) * 1.44269504f;
  }
  float wv[RK];
  {
    size_t wrow = (size_t)(k*DI + d)*RK;
    float4 w0 = ld4<BF>(Wdt, wrow), w1 = ld4<BF>(Wdt, wrow+4), w2 = ld4<BF>(Wdt, wrow+8);
    wv[0]=w0.x; wv[1]=w0.y; wv[2]=w0.z; wv[3]=w0.w;
    wv[4]=w1.x; wv[5]=w1.y; wv[6]=w1.z; wv[7]=w1.w;
    wv[8]=w2.x; wv[9]=w2.y; wv[10]=w2.z; wv[11]=w2.w;
  }
  const float bv = ld1<BF>(biasw, k*DI + d);
  float h[8];
  #pragma unroll
  for(int n = 0; n < 8; ++n) h[n] = 0.f;
  float sdt = 0.f;
  __syncthreads();
  const float* yrow = Yin + (size_t)b*LLEN*DI + d;
  int p = p0;
  #pragma unroll 2
  for(int j = 0; j < CLEN; ++j){
    float4 q0 = *(const float4*)&pr[j][0];
    float4 q1 = *(const float4*)&pr[j][4];
    float4 q2 = *(const float4*)&pr[j][8];
    float a = bv + q0.x*wv[0] + q0.y*wv[1] + q0.z*wv[2] + q0.w*wv[3]
                 + q1.x*wv[4] + q1.y*wv[5] + q1.z*wv[6] + q1.w*wv[7]
                 + q2.x*wv[8] + q2.y*wv[9] + q2.z*wv[10] + q2.w*wv[11];
    float dt = softplusf(a);
    float u  = yrow[(size_t)p*DI];
    sdt += dt;
    float dtu = dt*u;
    float4 b0 = *(const float4*)&bs[j][nh*8];
    float4 b1 = *(const float4*)&bs[j][nh*8+4];
    h[0] = __builtin_amdgcn_exp2f(dt*as2[0])*h[0] + dtu*b0.x;
    h[1] = __builtin_amdgcn_exp2f(dt*as2[1])*h[1] + dtu*b0.y;
    h[2] = __builtin_amdgcn_exp2f(dt*as2[2])*h[2] + dtu*b0.z;
    h[3] = __builtin_amdgcn_exp2f(dt*as2[3])*h[3] + dtu*b0.w;
    h[4] = __builtin_amdgcn_exp2f(dt*as2[4])*h[4] + dtu*b1.x;
    h[5] = __builtin_amdgcn_exp2f(dt*as2[5])*h[5] + dtu*b1.y;
    h[6] = __builtin_amdgcn_exp2f(dt*as2[6])*h[6] + dtu*b1.z;
    h[7] = __builtin_amdgcn_exp2f(dt*as2[7])*h[7] + dtu*b1.w;
    p += ps;
  }
  size_t base = ((size_t)(bk*DI + d)*NCH + ch)*NS + nh*8;
  *(float4*)(Sarr+base)   = make_float4(h[0],h[1],h[2],h[3]);
  *(float4*)(Sarr+base+4) = make_float4(h[4],h[5],h[6],h[7]);
  float pv[8];
  #pragma unroll
  for(int n = 0; n < 8; ++n) pv[n] = __builtin_amdgcn_exp2f(as2[n]*sdt);
  *(float4*)(Parr+base)   = make_float4(pv[0],pv[1],pv[2],pv[3]);
  *(float4*)(Parr+base+4) = make_float4(pv[4],pv[5],pv[6],pv[7]);
}
__global__ __launch_bounds__(384) void k_scan1(const float* dtsP, const float* Yin,
                                               const float* BC, const void* Alog,
                                               const void* Wdt, const void* biasw,
                                               float* Sarr, float* Parr, const uint32* flag){
  __shared__ float bs[CLEN][NS];
  __shared__ float pr[CLEN][RK];
  if(*flag) scan1_impl<true>(dtsP, Yin, BC, Alog, Wdt, biasw, Sarr, Parr, bs, pr);
  else      scan1_impl<false>(dtsP, Yin, BC, Alog, Wdt, biasw, Sarr, Parr, bs, pr);
}

// ---------------- K3b: cross-chunk prefix (in-place: Sarr becomes h_in per chunk) -------------
__global__ __launch_bounds__(256) void k_scan2(float* __restrict__ Sarr,
                                               const float* __restrict__ Parr){
  int tid = blockIdx.x*256 + threadIdx.x;   // 49152 = B*K*D*N
  int n = tid & 15;
  int bkd = tid >> 4;
  float h = 0.f;
  for(int c = 0; c < NCH; ++c){
    size_t i = ((size_t)bkd*NCH + c)*NS + n;
    float s = Sarr[i], p = Parr[i];
    Sarr[i] = h;
    h = p*h + s;
  }
}

// ---------------- K3c: scan phase 3; n-split-2; atomic-accumulate y at spatial pos -----------
template<bool BF>
__device__ void scan3_impl(const float* dtsP, const float* Yin, const float* BC,
                           const void* Alog, const void* Wdt, const void* biasw,
                           const void* DsI, const float* Hin, float* Acc,
                           float (*bs)[32], float (*pr)[RK]){
  const int blk = blockIdx.x;
  const int ch = blk % NCH;
  const int bk = blk / NCH;
  const int k  = bk % KKDIR;
  const int b  = bk / KKDIR;
  const int t  = threadIdx.x;
  const int d  = t >> 1;
  const int nh = t & 1;
  const int l0 = ch * CLEN;
  const int p0 = perm_p0(k, l0);
  const int ps = perm_ps(k);
  for(int idx = t; idx < CLEN*32; idx += 384){
    int j = idx >> 5, n = idx & 31;
    bs[j][n] = BC[((size_t)bk*LLEN + p0 + ps*j)*32 + n];
  }
  for(int idx = t; idx < CLEN*RK; idx += 384){
    int j = idx / RK, r = idx - j*RK;
    pr[j][r] = dtsP[((size_t)bk*LLEN + p0 + ps*j)*RK + r];
  }
  float as2[8];
  {
    size_t arow = (size_t)(k*DI + d)*NS + nh*8;
    #pragma unroll
    for(int n = 0; n < 8; ++n) as2[n] = -__expf(ld1<BF>(Alog, arow + n)) * 1.44269504f;
  }
  float wv[RK];
  {
    size_t wrow = (size_t)(k*DI + d)*RK;
    float4 w0 = ld4<BF>(Wdt, wrow), w1 = ld4<BF>(Wdt, wrow+4), w2 = ld4<BF>(Wdt, wrow+8);
    wv[0]=w0.x; wv[1]=w0.y; wv[2]=w0.z; wv[3]=w0.w;
    wv[4]=w1.x; wv[5]=w1.y; wv[6]=w1.z; wv[7]=w1.w;
    wv[8]=w2.x; wv[9]=w2.y; wv[10]=w2.z; wv[11]=w2.w;
  }
  const float bv = ld1<BF>(biasw, k*DI + d);
  const float dsv = ld1<BF>(DsI, k*DI + d);
  float h[8];
  {
    size_t hbase = ((size_t)(bk*DI + d)*NCH + ch)*NS + nh*8;
    float4 h0 = *(const float4*)(Hin + hbase);
    float4 h1 = *(const float4*)(Hin + hbase + 4);
    h[0]=h0.x; h[1]=h0.y; h[2]=h0.z; h[3]=h0.w;
    h[4]=h1.x; h[5]=h1.y; h[6]=h1.z; h[7]=h1.w;
  }
  __syncthreads();
  const float* yrow = Yin + (size_t)b*LLEN*DI + d;
  float* arow = Acc + (size_t)b*LLEN*DI + d;
  int p = p0;
  #pragma unroll 2
  for(int j = 0; j < CLEN; ++j){
    float4 q0 = *(const float4*)&pr[j][0];
    float4 q1 = *(const float4*)&pr[j][4];
    float4 q2 = *(const float4*)&pr[j][8];
    float a = bv + q0.x*wv[0] + q0.y*wv[1] + q0.z*wv[2] + q0.w*wv[3]
                 + q1.x*wv[4] + q1.y*wv[5] + q1.z*wv[6] + q1.w*wv[7]
                 + q2.x*wv[8] + q2.y*wv[9] + q2.z*wv[10] + q2.w*wv[11];
    float dt = softplusf(a);
    float u  = yrow[(size_t)p*DI];
    float dtu = dt*u;
    float4 b0 = *(const float4*)&bs[j][nh*8];
    float4 b1 = *(const float4*)&bs[j][nh*8+4];
    float4 c0 = *(const float4*)&bs[j][16+nh*8];
    float4 c1 = *(const float4*)&bs[j][16+nh*8+4];
    float y = (nh == 0) ? dsv*u : 0.f;
    h[0] = __builtin_amdgcn_exp2f(dt*as2[0])*h[0] + dtu*b0.x;  y += h[0]*c0.x;
    h[1] = __builtin_amdgcn_exp2f(dt*as2[1])*h[1] + dtu*b0.y;  y += h[1]*c0.y;
    h[2] = __builtin_amdgcn_exp2f(dt*as2[2])*h[2] + dtu*b0.z;  y += h[2]*c0.z;
    h[3] = __builtin_amdgcn_exp2f(dt*as2[3])*h[3] + dtu*b0.w;  y += h[3]*c0.w;
    h[4] = __builtin_amdgcn_exp2f(dt*as2[4])*h[4] + dtu*b1.x;  y += h[4]*c1.x;
    h[5] = __builtin_amdgcn_exp2f(dt*as2[5])*h[5] + dtu*b1.y;  y += h[5]*c1.y;
    h[6] = __builtin_amdgcn_exp2f(dt*as2[6])*h[6] + dtu*b1.z;  y += h[6]*c1.z;
    h[7] = __builtin_amdgcn_exp2f(dt*as2[7])*h[7] + dtu*b1.w;  y += h[7]*c1.w;
    y += __shfl_xor(y, 1);
    if(nh == 0) atomicAdd(arow + (size_t)p*DI, y);  // involution: seq l emits at spatial p
    p += ps;
  }
}
__global__ __launch_bounds__(384) void k_scan3(const float* dtsP, const float* Yin,
                                               const float* BC, const void* Alog,
                                               const void* Wdt, const void* biasw,
                                               const void* DsI, const float* Hin,
                                               float* Acc, const uint32* flag){
  __shared__ float bs[CLEN][32];
  __shared__ float pr[CLEN][RK];
  if(*flag) scan3_impl<true>(dtsP, Yin, BC, Alog, Wdt, biasw, DsI, Hin, Acc, bs, pr);
  else      scan3_impl<false>(dtsP, Yin, BC, Alog, Wdt, biasw, DsI, Hin, Acc, bs, pr);
}

// ---------------- K4: LayerNorm + out_proj + store (64 rows x 96 cols per block) ----------
// grid 512: b = blk>>7, lblk = (blk>>1)&63, chalf = blk&1. 2 blocks/CU (52KB LDS).
template<bool BF>
__device__ void post_impl(const float* Acc, const void* gamma, const void* beta,
                          const void* Wout, void* Out,
                          float (*ym)[YPAD], float* mu, float* rs,
                          float* gs, float* bt){
  const int b     = blockIdx.x >> 7;
  const int l0    = ((blockIdx.x >> 1) & 63) << 6;
  const int chalf = blockIdx.x & 1;
  const int t     = threadIdx.x;
  // stage gamma/beta
  if(t < DI){ gs[t] = ld1<BF>(gamma, t); bt[t] = ld1<BF>(beta, t); }
  // A: load 64x192 rows
  for(int idx = t; idx < 64*48; idx += 256){
    int l = idx / 48, d4 = (idx % 48) * 4;
    float4 v = *(const float4*)(Acc + ((size_t)b*LLEN + l0 + l)*DI + d4);
    ym[l][d4] = v.x; ym[l][d4+1] = v.y; ym[l][d4+2] = v.z; ym[l][d4+3] = v.w;
  }
  __syncthreads();
  // B: LN stats (4 threads per row)
  const int row = t >> 2, sub = t & 3;
  {
    float s1 = 0.f, s2 = 0.f;
    #pragma unroll 8
    for(int j = 0; j < 48; ++j){
      float v = ym[row][sub*48 + j];
      s1 += v; s2 += v*v;
    }
    s1 += __shfl_xor(s1, 1); s2 += __shfl_xor(s2, 1);
    s1 += __shfl_xor(s1, 2); s2 += __shfl_xor(s2, 2);
    if(sub == 0){
      float mean = s1 * (1.f/192.f);
      float var  = s2 * (1.f/192.f) - mean*mean;
      mu[row] = mean;
      rs[row] = rsqrtf(var + 1e-5f);
    }
  }
  __syncthreads();
  // C: normalize + affine in-place
  {
    float m = mu[row], r = rs[row];
    #pragma unroll 8
    for(int j = 0; j < 48; ++j){
      int d = sub*48 + j;
      ym[row][d] = (ym[row][d] - m) * r * gs[d] + bt[d];
    }
  }
  __syncthreads();
  // D: GEMM 64l x 96c: thread = (lg = t&15 -> 4 l, cg = t>>4 -> 6 c)
  {
    const int lg = t & 15, cg = t >> 4;
    const int c0 = chalf*96 + cg*6;
    float acc[24];
    #pragma unroll
    for(int i = 0; i < 24; ++i) acc[i] = 0.f;
    for(int dd = 0; dd < DI; ++dd){
      float x0 = ym[lg*4+0][dd];
      float x1 = ym[lg*4+1][dd];
      float x2 = ym[lg*4+2][dd];
      float x3 = ym[lg*4+3][dd];
      size_t wrow = (size_t)dd*DI + c0;
      float4 wA = ld4<BF>(Wout, wrow);
      float2 wB = ld2<BF>(Wout, wrow + 4);
      float w[6] = {wA.x, wA.y, wA.z, wA.w, wB.x, wB.y};
      #pragma unroll
      for(int jc = 0; jc < 6; ++jc){
        acc[jc*4+0] += x0*w[jc];
        acc[jc*4+1] += x1*w[jc];
        acc[jc*4+2] += x2*w[jc];
        acc[jc*4+3] += x3*w[jc];
      }
    }
    #pragma unroll
    for(int jc = 0; jc < 6; ++jc){
      int c = c0 + jc;
      st4<BF>(Out, ((size_t)b*DI + c)*LLEN + l0 + lg*4,
              acc[jc*4+0], acc[jc*4+1], acc[jc*4+2], acc[jc*4+3]);
    }
  }
}
__global__ __launch_bounds__(256) void k_post(const float* Acc, const void* gamma,
                                              const void* beta, const void* Wout,
                                              void* Out, const uint32* flag){
  __shared__ float ym[64][YPAD];
  __shared__ float mu[64], rs[64];
  __shared__ float gs[DI], bt[DI];
  if(*flag) post_impl<true>(Acc, gamma, beta, Wout, Out, ym, mu, rs, gs, bt);
  else      post_impl<false>(Acc, gamma, beta, Wout, Out, ym, mu, rs, gs, bt);
}

extern "C" void kernel_launch(void* const* d_in, const int* in_sizes, int n_in,
                              void* d_out, int out_size, void* d_ws, size_t ws_size,
                              hipStream_t stream){
  (void)in_sizes; (void)n_in; (void)out_size; (void)ws_size;
  const void* x    = d_in[0];
  const void* y    = d_in[1];
  const void* wx   = d_in[2];
  const void* wy   = d_in[3];
  const void* xpw  = d_in[4];
  const void* wdt  = d_in[5];
  const void* dtb  = d_in[6];
  const void* alog = d_in[7];
  const void* dsv  = d_in[8];
  const void* gam  = d_in[9];
  const void* bet  = d_in[10];
  const void* wout = d_in[11];

  float* ws   = (float*)d_ws;
  uint32* flag = (uint32*)ws;                                  // 16-float pad
  float* xin  = ws + 16;                                       // BLD
  float* yin  = xin  + BLD;                                    // BLD
  float* dtsP = yin  + BLD;                                    // B*K*L*12
  float* bc   = dtsP + (size_t)BATCH*KKDIR*LLEN*RK;            // B*K*L*32
  float* acc  = bc   + (size_t)BATCH*KKDIR*LLEN*32;            // BLD
  float* sarr = acc  + BLD;                                    // B*K*D*NCH*NS
  float* parr = sarr + (size_t)BATCH*KKDIR*DI*NCH*NS;          // B*K*D*NCH*NS
  // total: 16 + 3*BLD + 0.786M + 2.097M + 2*3.146M floats ~= 74.5 MB

  k_detect<<<1, 64, 0, stream>>>(alog, flag);
  hipMemsetAsync(acc, 0, BLD*sizeof(float), stream);
  k_inproj<<<256, 256, 0, stream>>>(x, wx, xin, flag);
  k_inproj<<<256, 256, 0, stream>>>(y, wy, yin, flag);
  k_proj<<<512, 256, 0, stream>>>(xin, xpw, dtsP, bc, flag);
  k_scan1<<<BATCH*KKDIR*NCH, 384, 0, stream>>>(dtsP, yin, bc, alog, wdt, dtb, sarr, parr, flag);
  k_scan2<<<192, 256, 0, stream>>>(sarr, parr);
  k_scan3<<<BATCH*KKDIR*NCH, 384, 0, stream>>>(dtsP, yin, bc, alog, wdt, dtb, dsv, sarr, acc, flag);
  k_post<<<BATCH*64*2, 256, 0, stream>>>(acc, gam, bet, wout, d_out, flag);
}

// Round 6
// 358.306 us; speedup vs baseline: 1.5199x; 1.0132x over previous
//
#include <hip/hip_runtime.h>

typedef unsigned int uint32;
typedef unsigned short ushort_t;

#define BATCH 4
#define DI    192   // d_inner == d_model
#define KKDIR 4
#define NS    16    // d_state
#define RK    12    // dt_rank
#define LLEN  4096  // H*W
#define CDBL  44    // RK + 2*NS
#define NCH   64    // scan chunks
#define CLEN  64    // chunk length
#define BLD   ((size_t)BATCH*LLEN*DI)
#define YPAD  205   // 205%32=13 -> GEMM-phase LDS reads land 2/bank (free)

__device__ __forceinline__ float bf2f(ushort_t u){
  union { uint32 i; float f; } v; v.i = ((uint32)u) << 16; return v.f;
}
__device__ __forceinline__ ushort_t f2bf(float f){
  union { float f; uint32 i; } v; v.f = f;
  return (ushort_t)((v.i + 0x7fffu + ((v.i >> 16) & 1u)) >> 16);
}
// dual-dtype loads: BF=true -> packed bf16, BF=false -> fp32
template<bool BF> __device__ __forceinline__ float ld1(const void* p, size_t i){
  if(BF) return bf2f(((const ushort_t*)p)[i]);
  return ((const float*)p)[i];
}
template<bool BF> __device__ __forceinline__ float2 ld2(const void* p, size_t i){
  if(BF){
    uint32 w = *(const uint32*)(((const ushort_t*)p) + i);
    return make_float2(bf2f((ushort_t)(w & 0xffffu)), bf2f((ushort_t)(w >> 16)));
  }
  return *(const float2*)(((const float*)p) + i);
}
template<bool BF> __device__ __forceinline__ float4 ld4(const void* p, size_t i){
  if(BF){
    uint2 w = *(const uint2*)(((const ushort_t*)p) + i);
    return make_float4(bf2f((ushort_t)(w.x & 0xffffu)), bf2f((ushort_t)(w.x >> 16)),
                       bf2f((ushort_t)(w.y & 0xffffu)), bf2f((ushort_t)(w.y >> 16)));
  }
  return *(const float4*)(((const float*)p) + i);
}
struct __attribute__((aligned(8))) us4 { ushort_t x, y, z, w; };
template<bool BF> __device__ __forceinline__ void st4(void* p, size_t i,
                                                      float a, float b, float c, float d){
  if(BF){
    us4 v; v.x = f2bf(a); v.y = f2bf(b); v.z = f2bf(c); v.w = f2bf(d);
    *(us4*)(((ushort_t*)p) + i) = v;
  } else {
    *(float4*)(((float*)p) + i) = make_float4(a, b, c, d);
  }
}
// direction k: sequence position l maps to spatial p = p0(k,l0) + ps(k)*j within an
// aligned 64-chunk (l0 = ch*CLEN, CLEN=64). permk is an involution.
__device__ __forceinline__ int perm_p0(int k, int l0){
  if(k == 0) return l0;
  if(k == 1) return l0 >> 6;
  if(k == 2) return 4095 - l0;
  return 4095 - (l0 >> 6);
}
__device__ __forceinline__ int perm_ps(int k){
  if(k == 0) return 1;
  if(k == 1) return 64;
  if(k == 2) return -1;
  return -64;
}
__device__ __forceinline__ float softplusf(float a){
  return fmaxf(a, 0.f) + __logf(1.f + __expf(-fabsf(a)));
}

// ---------------- K0: dtype detect (A_logs[0]==log(1)==0.0f iff fp32) ----------------
__global__ void k_detect(const void* alog, uint32* flag){
  if(threadIdx.x == 0 && blockIdx.x == 0)
    *flag = (*(const uint32*)alog != 0u) ? 1u : 0u;
}

// ---------------- K1: input projection  Xout[b,l,d] = sum_c X[b,c,l]*W[c,d] ----------------
template<bool BF>
__device__ void inproj_impl(const void* X, const void* Wm, float* Xout, float (*xs)[64]){
  const int b  = blockIdx.x >> 6;
  const int l0 = (blockIdx.x & 63) << 6;
  const int t  = threadIdx.x;
  for(int idx = t; idx < DI*64; idx += 256){
    int c = idx >> 6, lc = idx & 63;
    xs[c][lc] = ld1<BF>(X, (size_t)(b*DI + c)*LLEN + l0 + lc);
  }
  __syncthreads();
  #pragma unroll
  for(int it = 0; it < 3; ++it){
    int item = it*256 + t;      // 48 d-groups x 16 l-groups
    int dg = item % 48;
    int lg = item / 48;
    float a00=0,a01=0,a02=0,a03=0,a10=0,a11=0,a12=0,a13=0;
    float a20=0,a21=0,a22=0,a23=0,a30=0,a31=0,a32=0,a33=0;
    #pragma unroll 4
    for(int c = 0; c < DI; ++c){
      float4 w = ld4<BF>(Wm, (size_t)c*DI + dg*4);
      float4 xv = *(const float4*)&xs[c][lg*4];
      a00 += xv.x*w.x; a01 += xv.x*w.y; a02 += xv.x*w.z; a03 += xv.x*w.w;
      a10 += xv.y*w.x; a11 += xv.y*w.y; a12 += xv.y*w.z; a13 += xv.y*w.w;
      a20 += xv.z*w.x; a21 += xv.z*w.y; a22 += xv.z*w.z; a23 += xv.z*w.w;
      a30 += xv.w*w.x; a31 += xv.w*w.y; a32 += xv.w*w.z; a33 += xv.w*w.w;
    }
    size_t rb = ((size_t)b*LLEN + l0 + lg*4)*DI + dg*4;
    *(float4*)(Xout + rb)        = make_float4(a00,a01,a02,a03);
    *(float4*)(Xout + rb + DI)   = make_float4(a10,a11,a12,a13);
    *(float4*)(Xout + rb + 2*DI) = make_float4(a20,a21,a22,a23);
    *(float4*)(Xout + rb + 3*DI) = make_float4(a30,a31,a32,a33);
  }
}
__global__ __launch_bounds__(256) void k_inproj(const void* X, const void* Wm,
                                                float* Xout, const uint32* flag){
  __shared__ float xs[DI][64];
  if(*flag) inproj_impl<true>(X, Wm, Xout, xs);
  else      inproj_impl<false>(X, Wm, Xout, xs);
}

// ---------------- K2: direction projections as K-tiled GEMM -> dtsP, B/C ----------------
// C[64 pl x 96 cpad] per block; cpad = k*48 + j (j<12 dts, 12<=j<44 B/C, j>=44 pad).
// grid 512: b = blk>>7, lb = (blk>>1)&63, chalf = blk&1.
template<bool BF>
__device__ void proj_impl(const float* Xin, const void* Wp,
                          float* dtsP, float* BC,
                          float (*xs)[68], float (*wsb)[100]){
  const int b     = blockIdx.x >> 7;
  const int lb    = (blockIdx.x >> 1) & 63;
  const int chalf = blockIdx.x & 1;
  const int p0    = lb << 6;
  const int c0    = chalf * 96;
  const int t     = threadIdx.x;
  const int lg    = t & 15;         // 4 pl rows
  const int cg    = t >> 4;         // 6 c cols
  float acc[24];
  #pragma unroll
  for(int i = 0; i < 24; ++i) acc[i] = 0.f;

  for(int kt = 0; kt < 6; ++kt){
    // stage X tile transposed: xs[dd][pl], dd = kt*32..+31
    #pragma unroll
    for(int it = 0; it < 2; ++it){
      int i = it*256 + t;           // 512 items
      int pl = i >> 3, dq = i & 7;
      float4 v = *(const float4*)(Xin + ((size_t)b*LLEN + p0 + pl)*DI + kt*32 + dq*4);
      xs[dq*4+0][pl] = v.x; xs[dq*4+1][pl] = v.y;
      xs[dq*4+2][pl] = v.z; xs[dq*4+3][pl] = v.w;
    }
    // stage W tile unpacked fp32: wsb[dd][cp], cp = 0..95 (global cpad = c0+cp)
    #pragma unroll
    for(int it = 0; it < 6; ++it){
      int i = it*256 + t;           // 1536 items
      int cp = i >> 4, dp = (i & 15) * 2;
      int cpad = c0 + cp;
      int k = cpad / 48, j = cpad % 48;
      float2 v = (j < CDBL) ? ld2<BF>(Wp, (size_t)(k*CDBL + j)*DI + kt*32 + dp)
                            : make_float2(0.f, 0.f);
      wsb[dp][cp] = v.x; wsb[dp+1][cp] = v.y;
    }
    __syncthreads();
    #pragma unroll 4
    for(int dd = 0; dd < 32; ++dd){
      float4 xv = *(const float4*)&xs[dd][lg*4];
      float2 w0 = *(const float2*)&wsb[dd][cg*6];
      float2 w1 = *(const float2*)&wsb[dd][cg*6+2];
      float2 w2 = *(const float2*)&wsb[dd][cg*6+4];
      float w[6] = {w0.x, w0.y, w1.x, w1.y, w2.x, w2.y};
      #pragma unroll
      for(int jc = 0; jc < 6; ++jc){
        acc[0*6+jc] += xv.x*w[jc];
        acc[1*6+jc] += xv.y*w[jc];
        acc[2*6+jc] += xv.z*w[jc];
        acc[3*6+jc] += xv.w*w[jc];
      }
    }
    __syncthreads();
  }
  // epilogue: cpad = c0 + cg*6 + jc; one k per thread (48/6=8 cg-groups per k)
  const int cpad0 = c0 + cg*6;
  const int k  = cpad0 / 48;
  const int j0 = cpad0 % 48;
  #pragma unroll
  for(int pl = 0; pl < 4; ++pl){
    int p = p0 + lg*4 + pl;
    size_t rowbase = ((size_t)(b*KKDIR + k)*LLEN + p);
    #pragma unroll
    for(int jc = 0; jc < 6; ++jc){
      int j = j0 + jc;
      float v = acc[pl*6 + jc];
      if(j < RK)         dtsP[rowbase*RK + j] = v;
      else if(j < CDBL)  BC[rowbase*32 + (j - RK)] = v;
      // j >= 44: pad, discard
    }
  }
}
__global__ __launch_bounds__(256) void k_proj(const float* Xin, const void* Wp,
                                              float* dtsP, float* BC, const uint32* flag){
  __shared__ float xs[32][68];
  __shared__ float wsb[32][100];
  if(*flag) proj_impl<true>(Xin, Wp, dtsP, BC, xs, wsb);
  else      proj_impl<false>(Xin, Wp, dtsP, BC, xs, wsb);
}

// ---------------- K2b: expand dtsP -> delta = softplus(dts@Wdt + bias), fp16 [B,K,L,D] -----
template<bool BF>
__device__ void delta_impl(const float* dtsP, const void* Wdt, const void* biasw,
                           _Float16* Delta, float (*ds)[RK]){
  const int blk = blockIdx.x;
  const int bk  = blk >> 6;           // b*K + k
  const int p0  = (blk & 63) << 6;
  const int k   = bk & 3;
  const int d   = threadIdx.x;
  for(int idx = d; idx < 64*RK; idx += 192){
    int j = idx / RK, r = idx - j*RK;
    ds[j][r] = dtsP[((size_t)bk*LLEN + p0 + j)*RK + r];
  }
  float wv[RK];
  {
    size_t wrow = (size_t)(k*DI + d)*RK;
    float4 w0 = ld4<BF>(Wdt, wrow), w1 = ld4<BF>(Wdt, wrow+4), w2 = ld4<BF>(Wdt, wrow+8);
    wv[0]=w0.x; wv[1]=w0.y; wv[2]=w0.z; wv[3]=w0.w;
    wv[4]=w1.x; wv[5]=w1.y; wv[6]=w1.z; wv[7]=w1.w;
    wv[8]=w2.x; wv[9]=w2.y; wv[10]=w2.z; wv[11]=w2.w;
  }
  const float bv = ld1<BF>(biasw, k*DI + d);
  __syncthreads();
  _Float16* orow = Delta + (size_t)bk*LLEN*DI + d;
  #pragma unroll 4
  for(int j = 0; j < 64; ++j){
    float4 q0 = *(const float4*)&ds[j][0];
    float4 q1 = *(const float4*)&ds[j][4];
    float4 q2 = *(const float4*)&ds[j][8];
    float a = bv + q0.x*wv[0] + q0.y*wv[1] + q0.z*wv[2] + q0.w*wv[3]
                 + q1.x*wv[4] + q1.y*wv[5] + q1.z*wv[6] + q1.w*wv[7]
                 + q2.x*wv[8] + q2.y*wv[9] + q2.z*wv[10] + q2.w*wv[11];
    orow[(size_t)(p0 + j)*DI] = (_Float16)softplusf(a);
  }
}
__global__ __launch_bounds__(192) void k_delta(const float* dtsP, const void* Wdt,
                                               const void* biasw, _Float16* Delta,
                                               const uint32* flag){
  __shared__ float ds[64][RK];
  if(*flag) delta_impl<true>(dtsP, Wdt, biasw, Delta, ds);
  else      delta_impl<false>(dtsP, Wdt, biasw, Delta, ds);
}

// ---------------- K3a: chunked scan phase 1; n-split-2 (thread = d*2+nh, 8 states) ----------
template<bool BF>
__device__ void scan1_impl(const _Float16* Delta, const float* Yin, const float* BC,
                           const void* Alog, float* Sarr, float* Parr,
                           float (*bs)[NS]){
  const int blk = blockIdx.x;
  const int ch = blk % NCH;
  const int bk = blk / NCH;   // b*K + k
  const int k  = bk % KKDIR;
  const int b  = bk / KKDIR;
  const int t  = threadIdx.x;
  const int d  = t >> 1;
  const int nh = t & 1;       // which 8-state half
  const int l0 = ch * CLEN;
  const int p0 = perm_p0(k, l0);
  const int ps = perm_ps(k);
  for(int idx = t; idx < CLEN*NS; idx += 384){
    int j = idx >> 4, n = idx & 15;
    bs[j][n] = BC[((size_t)bk*LLEN + p0 + ps*j)*32 + n];
  }
  float as2[8];
  {
    size_t arow = (size_t)(k*DI + d)*NS + nh*8;
    #pragma unroll
    for(int n = 0; n < 8; ++n) as2[n] = -__expf(ld1<BF>(Alog, arow + n)) * 1.44269504f;
  }
  float h[8];
  #pragma unroll
  for(int n = 0; n < 8; ++n) h[n] = 0.f;
  float sdt = 0.f;
  __syncthreads();
  const _Float16* drow = Delta + (size_t)bk*LLEN*DI + d;
  const float* yrow = Yin + (size_t)b*LLEN*DI + d;
  int p = p0;
  #pragma unroll 2
  for(int j = 0; j < CLEN; ++j){
    float dt = (float)drow[(size_t)p*DI];
    float u  = yrow[(size_t)p*DI];
    sdt += dt;
    float dtu = dt*u;
    float4 b0 = *(const float4*)&bs[j][nh*8];
    float4 b1 = *(const float4*)&bs[j][nh*8+4];
    h[0] = __builtin_amdgcn_exp2f(dt*as2[0])*h[0] + dtu*b0.x;
    h[1] = __builtin_amdgcn_exp2f(dt*as2[1])*h[1] + dtu*b0.y;
    h[2] = __builtin_amdgcn_exp2f(dt*as2[2])*h[2] + dtu*b0.z;
    h[3] = __builtin_amdgcn_exp2f(dt*as2[3])*h[3] + dtu*b0.w;
    h[4] = __builtin_amdgcn_exp2f(dt*as2[4])*h[4] + dtu*b1.x;
    h[5] = __builtin_amdgcn_exp2f(dt*as2[5])*h[5] + dtu*b1.y;
    h[6] = __builtin_amdgcn_exp2f(dt*as2[6])*h[6] + dtu*b1.z;
    h[7] = __builtin_amdgcn_exp2f(dt*as2[7])*h[7] + dtu*b1.w;
    p += ps;
  }
  size_t base = ((size_t)(bk*DI + d)*NCH + ch)*NS + nh*8;
  *(float4*)(Sarr+base)   = make_float4(h[0],h[1],h[2],h[3]);
  *(float4*)(Sarr+base+4) = make_float4(h[4],h[5],h[6],h[7]);
  float pv[8];
  #pragma unroll
  for(int n = 0; n < 8; ++n) pv[n] = __builtin_amdgcn_exp2f(as2[n]*sdt);
  *(float4*)(Parr+base)   = make_float4(pv[0],pv[1],pv[2],pv[3]);
  *(float4*)(Parr+base+4) = make_float4(pv[4],pv[5],pv[6],pv[7]);
}
__global__ __launch_bounds__(384) void k_scan1(const _Float16* Delta, const float* Yin,
                                               const float* BC, const void* Alog,
                                               float* Sarr, float* Parr, const uint32* flag){
  __shared__ float bs[CLEN][NS];
  if(*flag) scan1_impl<true>(Delta, Yin, BC, Alog, Sarr, Parr, bs);
  else      scan1_impl<false>(Delta, Yin, BC, Alog, Sarr, Parr, bs);
}

// ---------------- K3b: cross-chunk prefix (in-place: Sarr becomes h_in per chunk) -------------
__global__ __launch_bounds__(256) void k_scan2(float* __restrict__ Sarr,
                                               const float* __restrict__ Parr){
  int tid = blockIdx.x*256 + threadIdx.x;   // 49152 = B*K*D*N
  int n = tid & 15;
  int bkd = tid >> 4;
  float h = 0.f;
  for(int c = 0; c < NCH; ++c){
    size_t i = ((size_t)bkd*NCH + c)*NS + n;
    float s = Sarr[i], p = Parr[i];
    Sarr[i] = h;
    h = p*h + s;
  }
}

// ---------------- K3c: scan phase 3; n-split-2; atomic-accumulate y at spatial pos -----------
template<bool BF>
__device__ void scan3_impl(const _Float16* Delta, const float* Yin, const float* BC,
                           const void* Alog, const void* DsI, const float* Hin,
                           float* Acc, float (*bs)[32]){
  const int blk = blockIdx.x;
  const int ch = blk % NCH;
  const int bk = blk / NCH;
  const int k  = bk % KKDIR;
  const int b  = bk / KKDIR;
  const int t  = threadIdx.x;
  const int d  = t >> 1;
  const int nh = t & 1;
  const int l0 = ch * CLEN;
  const int p0 = perm_p0(k, l0);
  const int ps = perm_ps(k);
  for(int idx = t; idx < CLEN*32; idx += 384){
    int j = idx >> 5, n = idx & 31;
    bs[j][n] = BC[((size_t)bk*LLEN + p0 + ps*j)*32 + n];
  }
  float as2[8];
  {
    size_t arow = (size_t)(k*DI + d)*NS + nh*8;
    #pragma unroll
    for(int n = 0; n < 8; ++n) as2[n] = -__expf(ld1<BF>(Alog, arow + n)) * 1.44269504f;
  }
  const float dsv = ld1<BF>(DsI, k*DI + d);
  float h[8];
  {
    size_t hbase = ((size_t)(bk*DI + d)*NCH + ch)*NS + nh*8;
    float4 h0 = *(const float4*)(Hin + hbase);
    float4 h1 = *(const float4*)(Hin + hbase + 4);
    h[0]=h0.x; h[1]=h0.y; h[2]=h0.z; h[3]=h0.w;
    h[4]=h1.x; h[5]=h1.y; h[6]=h1.z; h[7]=h1.w;
  }
  __syncthreads();
  const _Float16* drow = Delta + (size_t)bk*LLEN*DI + d;
  const float* yrow = Yin + (size_t)b*LLEN*DI + d;
  float* arow = Acc + (size_t)b*LLEN*DI + d;
  int p = p0;
  #pragma unroll 2
  for(int j = 0; j < CLEN; ++j){
    float dt = (float)drow[(size_t)p*DI];
    float u  = yrow[(size_t)p*DI];
    float dtu = dt*u;
    float4 b0 = *(const float4*)&bs[j][nh*8];
    float4 b1 = *(const float4*)&bs[j][nh*8+4];
    float4 c0 = *(const float4*)&bs[j][16+nh*8];
    float4 c1 = *(const float4*)&bs[j][16+nh*8+4];
    float y = (nh == 0) ? dsv*u : 0.f;
    h[0] = __builtin_amdgcn_exp2f(dt*as2[0])*h[0] + dtu*b0.x;  y += h[0]*c0.x;
    h[1] = __builtin_amdgcn_exp2f(dt*as2[1])*h[1] + dtu*b0.y;  y += h[1]*c0.y;
    h[2] = __builtin_amdgcn_exp2f(dt*as2[2])*h[2] + dtu*b0.z;  y += h[2]*c0.z;
    h[3] = __builtin_amdgcn_exp2f(dt*as2[3])*h[3] + dtu*b0.w;  y += h[3]*c0.w;
    h[4] = __builtin_amdgcn_exp2f(dt*as2[4])*h[4] + dtu*b1.x;  y += h[4]*c1.x;
    h[5] = __builtin_amdgcn_exp2f(dt*as2[5])*h[5] + dtu*b1.y;  y += h[5]*c1.y;
    h[6] = __builtin_amdgcn_exp2f(dt*as2[6])*h[6] + dtu*b1.z;  y += h[6]*c1.z;
    h[7] = __builtin_amdgcn_exp2f(dt*as2[7])*h[7] + dtu*b1.w;  y += h[7]*c1.w;
    y += __shfl_xor(y, 1);
    if(nh == 0) atomicAdd(arow + (size_t)p*DI, y);  // involution: seq l emits at spatial p
    p += ps;
  }
}
__global__ __launch_bounds__(384) void k_scan3(const _Float16* Delta, const float* Yin,
                                               const float* BC, const void* Alog,
                                               const void* DsI, const float* Hin,
                                               float* Acc, const uint32* flag){
  __shared__ float bs[CLEN][32];
  if(*flag) scan3_impl<true>(Delta, Yin, BC, Alog, DsI, Hin, Acc, bs);
  else      scan3_impl<false>(Delta, Yin, BC, Alog, DsI, Hin, Acc, bs);
}

// ---------------- K4: LayerNorm + out_proj + store (64 rows x 96 cols per block) ----------
// grid 512: b = blk>>7, lblk = (blk>>1)&63, chalf = blk&1. 2 blocks/CU (52KB LDS).
template<bool BF>
__device__ void post_impl(const float* Acc, const void* gamma, const void* beta,
                          const void* Wout, void* Out,
                          float (*ym)[YPAD], float* mu, float* rs,
                          float* gs, float* bt){
  const int b     = blockIdx.x >> 7;
  const int l0    = ((blockIdx.x >> 1) & 63) << 6;
  const int chalf = blockIdx.x & 1;
  const int t     = threadIdx.x;
  // stage gamma/beta
  if(t < DI){ gs[t] = ld1<BF>(gamma, t); bt[t] = ld1<BF>(beta, t); }
  // A: load 64x192 rows
  for(int idx = t; idx < 64*48; idx += 256){
    int l = idx / 48, d4 = (idx % 48) * 4;
    float4 v = *(const float4*)(Acc + ((size_t)b*LLEN + l0 + l)*DI + d4);
    ym[l][d4] = v.x; ym[l][d4+1] = v.y; ym[l][d4+2] = v.z; ym[l][d4+3] = v.w;
  }
  __syncthreads();
  // B: LN stats (4 threads per row)
  const int row = t >> 2, sub = t & 3;
  {
    float s1 = 0.f, s2 = 0.f;
    #pragma unroll 8
    for(int j = 0; j < 48; ++j){
      float v = ym[row][sub*48 + j];
      s1 += v; s2 += v*v;
    }
    s1 += __shfl_xor(s1, 1); s2 += __shfl_xor(s2, 1);
    s1 += __shfl_xor(s1, 2); s2 += __shfl_xor(s2, 2);
    if(sub == 0){
      float mean = s1 * (1.f/192.f);
      float var  = s2 * (1.f/192.f) - mean*mean;
      mu[row] = mean;
      rs[row] = rsqrtf(var + 1e-5f);
    }
  }
  __syncthreads();
  // C: normalize + affine in-place
  {
    float m = mu[row], r = rs[row];
    #pragma unroll 8
    for(int j = 0; j < 48; ++j){
      int d = sub*48 + j;
      ym[row][d] = (ym[row][d] - m) * r * gs[d] + bt[d];
    }
  }
  __syncthreads();
  // D: GEMM 64l x 96c: thread = (lg = t&15 -> 4 l, cg = t>>4 -> 6 c)
  {
    const int lg = t & 15, cg = t >> 4;
    const int c0 = chalf*96 + cg*6;
    float acc[24];
    #pragma unroll
    for(int i = 0; i < 24; ++i) acc[i] = 0.f;
    for(int dd = 0; dd < DI; ++dd){
      float x0 = ym[lg*4+0][dd];
      float x1 = ym[lg*4+1][dd];
      float x2 = ym[lg*4+2][dd];
      float x3 = ym[lg*4+3][dd];
      size_t wrow = (size_t)dd*DI + c0;
      float4 wA = ld4<BF>(Wout, wrow);
      float2 wB = ld2<BF>(Wout, wrow + 4);
      float w[6] = {wA.x, wA.y, wA.z, wA.w, wB.x, wB.y};
      #pragma unroll
      for(int jc = 0; jc < 6; ++jc){
        acc[jc*4+0] += x0*w[jc];
        acc[jc*4+1] += x1*w[jc];
        acc[jc*4+2] += x2*w[jc];
        acc[jc*4+3] += x3*w[jc];
      }
    }
    #pragma unroll
    for(int jc = 0; jc < 6; ++jc){
      int c = c0 + jc;
      st4<BF>(Out, ((size_t)b*DI + c)*LLEN + l0 + lg*4,
              acc[jc*4+0], acc[jc*4+1], acc[jc*4+2], acc[jc*4+3]);
    }
  }
}
__global__ __launch_bounds__(256) void k_post(const float* Acc, const void* gamma,
                                              const void* beta, const void* Wout,
                                              void* Out, const uint32* flag){
  __shared__ float ym[64][YPAD];
  __shared__ float mu[64], rs[64];
  __shared__ float gs[DI], bt[DI];
  if(*flag) post_impl<true>(Acc, gamma, beta, Wout, Out, ym, mu, rs, gs, bt);
  else      post_impl<false>(Acc, gamma, beta, Wout, Out, ym, mu, rs, gs, bt);
}

extern "C" void kernel_launch(void* const* d_in, const int* in_sizes, int n_in,
                              void* d_out, int out_size, void* d_ws, size_t ws_size,
                              hipStream_t stream){
  (void)in_sizes; (void)n_in; (void)out_size; (void)ws_size;
  const void* x    = d_in[0];
  const void* y    = d_in[1];
  const void* wx   = d_in[2];
  const void* wy   = d_in[3];
  const void* xpw  = d_in[4];
  const void* wdt  = d_in[5];
  const void* dtb  = d_in[6];
  const void* alog = d_in[7];
  const void* dsv  = d_in[8];
  const void* gam  = d_in[9];
  const void* bet  = d_in[10];
  const void* wout = d_in[11];

  float* ws   = (float*)d_ws;
  uint32* flag = (uint32*)ws;                                  // 16-float pad
  float* yin  = ws + 16;                                       // BLD
  float* dtsP = yin  + BLD;                                    // B*K*L*12
  float* bc   = dtsP + (size_t)BATCH*KKDIR*LLEN*RK;            // B*K*L*32
  float* acc  = bc   + (size_t)BATCH*KKDIR*LLEN*32;            // BLD
  float* sarr = acc  + BLD;                                    // B*K*D*NCH*NS
  float* parr = sarr + (size_t)BATCH*KKDIR*DI*NCH*NS;          // B*K*D*NCH*NS
  float* xreg = parr + (size_t)BATCH*KKDIR*DI*NCH*NS;          // union region:
  float* xin  = xreg;                                          //   fp32 B*L*D (12.6MB), dead after k_proj
  _Float16* delta = (_Float16*)xreg;                           //   fp16 B*K*L*D (25.2MB), written after
  // total: 16 + 5*BLD(yin,acc,sarr,parr + union 2*BLD-as-fp16) + small ~= 86.9 MB

  k_detect<<<1, 64, 0, stream>>>(alog, flag);
  hipMemsetAsync(acc, 0, BLD*sizeof(float), stream);
  k_inproj<<<256, 256, 0, stream>>>(x, wx, xin, flag);
  k_inproj<<<256, 256, 0, stream>>>(y, wy, yin, flag);
  k_proj<<<512, 256, 0, stream>>>(xin, xpw, dtsP, bc, flag);
  k_delta<<<BATCH*KKDIR*64, 192, 0, stream>>>(dtsP, wdt, dtb, delta, flag);
  k_scan1<<<BATCH*KKDIR*NCH, 384, 0, stream>>>(delta, yin, bc, alog, sarr, parr, flag);
  k_scan2<<<192, 256, 0, stream>>>(sarr, parr);
  k_scan3<<<BATCH*KKDIR*NCH, 384, 0, stream>>>(delta, yin, bc, alog, dsv, sarr, acc, flag);
  k_post<<<BATCH*64*2, 256, 0, stream>>>(acc, gam, bet, wout, d_out, flag);
}

// Round 7
// 318.153 us; speedup vs baseline: 1.7117x; 1.1262x over previous
//
#include <hip/hip_runtime.h>

typedef unsigned int uint32;
typedef unsigned short ushort_t;

#define BATCH 4
#define DI    192   // d_inner == d_model
#define KKDIR 4
#define NS    16    // d_state
#define RK    12    // dt_rank
#define LLEN  4096  // H*W
#define CDBL  44    // RK + 2*NS
#define NCH   64    // scan chunks
#define CLEN  64    // chunk length
#define BLD   ((size_t)BATCH*LLEN*DI)
#define YPAD  205   // 205%32=13 -> GEMM-phase LDS reads land 2/bank (free)

__device__ __forceinline__ float bf2f(ushort_t u){
  union { uint32 i; float f; } v; v.i = ((uint32)u) << 16; return v.f;
}
__device__ __forceinline__ ushort_t f2bf(float f){
  union { float f; uint32 i; } v; v.f = f;
  return (ushort_t)((v.i + 0x7fffu + ((v.i >> 16) & 1u)) >> 16);
}
template<bool BF> __device__ __forceinline__ float ld1(const void* p, size_t i){
  if(BF) return bf2f(((const ushort_t*)p)[i]);
  return ((const float*)p)[i];
}
template<bool BF> __device__ __forceinline__ float2 ld2(const void* p, size_t i){
  if(BF){
    uint32 w = *(const uint32*)(((const ushort_t*)p) + i);
    return make_float2(bf2f((ushort_t)(w & 0xffffu)), bf2f((ushort_t)(w >> 16)));
  }
  return *(const float2*)(((const float*)p) + i);
}
template<bool BF> __device__ __forceinline__ float4 ld4(const void* p, size_t i){
  if(BF){
    uint2 w = *(const uint2*)(((const ushort_t*)p) + i);
    return make_float4(bf2f((ushort_t)(w.x & 0xffffu)), bf2f((ushort_t)(w.x >> 16)),
                       bf2f((ushort_t)(w.y & 0xffffu)), bf2f((ushort_t)(w.y >> 16)));
  }
  return *(const float4*)(((const float*)p) + i);
}
struct __attribute__((aligned(8))) us4 { ushort_t x, y, z, w; };
template<bool BF> __device__ __forceinline__ void st4(void* p, size_t i,
                                                      float a, float b, float c, float d){
  if(BF){
    us4 v; v.x = f2bf(a); v.y = f2bf(b); v.z = f2bf(c); v.w = f2bf(d);
    *(us4*)(((ushort_t*)p) + i) = v;
  } else {
    *(float4*)(((float*)p) + i) = make_float4(a, b, c, d);
  }
}
__device__ __forceinline__ bool is_bf(const void* alog){
  return (*(const uint32*)alog) != 0u;   // A_logs[0]=log(1)=0.0f iff fp32
}
// direction k: spatial p = p0(k,l0) + ps(k)*j within an aligned 64-chunk; involution.
__device__ __forceinline__ int perm_p0(int k, int l0){
  if(k == 0) return l0;
  if(k == 1) return l0 >> 6;
  if(k == 2) return 4095 - l0;
  return 4095 - (l0 >> 6);
}
__device__ __forceinline__ int perm_ps(int k){
  if(k == 0) return 1;
  if(k == 1) return 64;
  if(k == 2) return -1;
  return -64;
}
__device__ __forceinline__ float softplusf(float a){
  return fmaxf(a, 0.f) + __logf(1.f + __expf(-fabsf(a)));
}
union PackCv { uint32 u; _Float16 h[2]; };

// ---------------- K1: input projections (x and y in one launch, 512 blocks) --------------
template<bool BF>
__device__ void inproj_impl(const void* X, const void* Wm, float* Xout,
                            float (*xs)[64], int b, int l0){
  const int t = threadIdx.x;
  for(int idx = t; idx < DI*64; idx += 256){
    int c = idx >> 6, lc = idx & 63;
    xs[c][lc] = ld1<BF>(X, (size_t)(b*DI + c)*LLEN + l0 + lc);
  }
  __syncthreads();
  #pragma unroll
  for(int it = 0; it < 3; ++it){
    int item = it*256 + t;      // 48 d-groups x 16 l-groups
    int dg = item % 48;
    int lg = item / 48;
    float a00=0,a01=0,a02=0,a03=0,a10=0,a11=0,a12=0,a13=0;
    float a20=0,a21=0,a22=0,a23=0,a30=0,a31=0,a32=0,a33=0;
    #pragma unroll 4
    for(int c = 0; c < DI; ++c){
      float4 w = ld4<BF>(Wm, (size_t)c*DI + dg*4);
      float4 xv = *(const float4*)&xs[c][lg*4];
      a00 += xv.x*w.x; a01 += xv.x*w.y; a02 += xv.x*w.z; a03 += xv.x*w.w;
      a10 += xv.y*w.x; a11 += xv.y*w.y; a12 += xv.y*w.z; a13 += xv.y*w.w;
      a20 += xv.z*w.x; a21 += xv.z*w.y; a22 += xv.z*w.z; a23 += xv.z*w.w;
      a30 += xv.w*w.x; a31 += xv.w*w.y; a32 += xv.w*w.z; a33 += xv.w*w.w;
    }
    size_t rb = ((size_t)b*LLEN + l0 + lg*4)*DI + dg*4;
    *(float4*)(Xout + rb)        = make_float4(a00,a01,a02,a03);
    *(float4*)(Xout + rb + DI)   = make_float4(a10,a11,a12,a13);
    *(float4*)(Xout + rb + 2*DI) = make_float4(a20,a21,a22,a23);
    *(float4*)(Xout + rb + 3*DI) = make_float4(a30,a31,a32,a33);
  }
}
__global__ __launch_bounds__(256) void k_inproj(const void* X, const void* Y,
                                                const void* Wx, const void* Wy,
                                                float* Xout, float* Yout,
                                                const void* alog){
  __shared__ float xs[DI][64];
  const int sel = blockIdx.x >> 8;
  const int blk = blockIdx.x & 255;
  const void* src = sel ? Y : X;
  const void* w   = sel ? Wy : Wx;
  float* dst      = sel ? Yout : Xout;
  const int b = blk >> 6, l0 = (blk & 63) << 6;
  if(is_bf(alog)) inproj_impl<true>(src, w, dst, xs, b, l0);
  else            inproj_impl<false>(src, w, dst, xs, b, l0);
}

// ---------------- K2: direction projections as K-tiled GEMM -> dtsP, B/C; zeroes Acc -------
// C[64 pl x 96 cpad] per block; cpad = k*48 + j (j<12 dts, 12<=j<44 B/C, j>=44 pad).
template<bool BF>
__device__ void proj_impl(const float* Xin, const void* Wp,
                          float* dtsP, float* BC, float* Acc,
                          float (*xs)[68], float (*wsb)[100]){
  const int b     = blockIdx.x >> 7;
  const int lb    = (blockIdx.x >> 1) & 63;
  const int chalf = blockIdx.x & 1;
  const int p0    = lb << 6;
  const int c0    = chalf * 96;
  const int t     = threadIdx.x;
  const int lg    = t & 15;
  const int cg    = t >> 4;
  // zero the Acc slab for this (b, p0..p0+63) — harness re-poisons ws each call
  if(chalf == 0){
    float4* arow = (float4*)(Acc + ((size_t)b*LLEN + p0)*DI);
    #pragma unroll
    for(int it = 0; it < 12; ++it) arow[it*256 + t] = make_float4(0.f,0.f,0.f,0.f);
  }
  float acc[24];
  #pragma unroll
  for(int i = 0; i < 24; ++i) acc[i] = 0.f;

  for(int kt = 0; kt < 6; ++kt){
    #pragma unroll
    for(int it = 0; it < 2; ++it){
      int i = it*256 + t;
      int pl = i >> 3, dq = i & 7;
      float4 v = *(const float4*)(Xin + ((size_t)b*LLEN + p0 + pl)*DI + kt*32 + dq*4);
      xs[dq*4+0][pl] = v.x; xs[dq*4+1][pl] = v.y;
      xs[dq*4+2][pl] = v.z; xs[dq*4+3][pl] = v.w;
    }
    #pragma unroll
    for(int it = 0; it < 6; ++it){
      int i = it*256 + t;
      int cp = i >> 4, dp = (i & 15) * 2;
      int cpad = c0 + cp;
      int k = cpad / 48, j = cpad % 48;
      float2 v = (j < CDBL) ? ld2<BF>(Wp, (size_t)(k*CDBL + j)*DI + kt*32 + dp)
                            : make_float2(0.f, 0.f);
      wsb[dp][cp] = v.x; wsb[dp+1][cp] = v.y;
    }
    __syncthreads();
    #pragma unroll 4
    for(int dd = 0; dd < 32; ++dd){
      float4 xv = *(const float4*)&xs[dd][lg*4];
      float2 w0 = *(const float2*)&wsb[dd][cg*6];
      float2 w1 = *(const float2*)&wsb[dd][cg*6+2];
      float2 w2 = *(const float2*)&wsb[dd][cg*6+4];
      float w[6] = {w0.x, w0.y, w1.x, w1.y, w2.x, w2.y};
      #pragma unroll
      for(int jc = 0; jc < 6; ++jc){
        acc[0*6+jc] += xv.x*w[jc];
        acc[1*6+jc] += xv.y*w[jc];
        acc[2*6+jc] += xv.z*w[jc];
        acc[3*6+jc] += xv.w*w[jc];
      }
    }
    __syncthreads();
  }
  const int cpad0 = c0 + cg*6;
  const int k  = cpad0 / 48;
  const int j0 = cpad0 % 48;
  #pragma unroll
  for(int pl = 0; pl < 4; ++pl){
    int p = p0 + lg*4 + pl;
    size_t rowbase = ((size_t)(b*KKDIR + k)*LLEN + p);
    #pragma unroll
    for(int jc = 0; jc < 6; ++jc){
      int j = j0 + jc;
      float v = acc[pl*6 + jc];
      if(j < RK)         dtsP[rowbase*RK + j] = v;
      else if(j < CDBL)  BC[rowbase*32 + (j - RK)] = v;
    }
  }
}
__global__ __launch_bounds__(256) void k_proj(const float* Xin, const void* Wp,
                                              float* dtsP, float* BC, float* Acc,
                                              const void* alog){
  __shared__ float xs[32][68];
  __shared__ float wsb[32][100];
  if(is_bf(alog)) proj_impl<true>(Xin, Wp, dtsP, BC, Acc, xs, wsb);
  else            proj_impl<false>(Xin, Wp, dtsP, BC, Acc, xs, wsb);
}

// ---------------- K2b: dtsP -> pack(dt, dt*u) fp16x2 [B,K,Lspatial,D] -------------------
template<bool BF>
__device__ void pack_impl(const float* dtsP, const float* Yin, const void* Wdt,
                          const void* biasw, uint32* Pack, float (*ds)[RK]){
  const int blk = blockIdx.x;
  const int bk  = blk >> 6;           // b*K + k
  const int p0  = (blk & 63) << 6;
  const int k   = bk & 3;
  const int b   = bk >> 2;
  const int d   = threadIdx.x;
  for(int idx = d; idx < 64*RK; idx += 192){
    int j = idx / RK, r = idx - j*RK;
    ds[j][r] = dtsP[((size_t)bk*LLEN + p0 + j)*RK + r];
  }
  float wv[RK];
  {
    size_t wrow = (size_t)(k*DI + d)*RK;
    float4 w0 = ld4<BF>(Wdt, wrow), w1 = ld4<BF>(Wdt, wrow+4), w2 = ld4<BF>(Wdt, wrow+8);
    wv[0]=w0.x; wv[1]=w0.y; wv[2]=w0.z; wv[3]=w0.w;
    wv[4]=w1.x; wv[5]=w1.y; wv[6]=w1.z; wv[7]=w1.w;
    wv[8]=w2.x; wv[9]=w2.y; wv[10]=w2.z; wv[11]=w2.w;
  }
  const float bv = ld1<BF>(biasw, k*DI + d);
  __syncthreads();
  const float* yrow = Yin + ((size_t)b*LLEN + p0)*DI + d;
  uint32* prow = Pack + ((size_t)bk*LLEN + p0)*DI + d;
  #pragma unroll 4
  for(int j = 0; j < 64; ++j){
    float4 q0 = *(const float4*)&ds[j][0];
    float4 q1 = *(const float4*)&ds[j][4];
    float4 q2 = *(const float4*)&ds[j][8];
    float a = bv + q0.x*wv[0] + q0.y*wv[1] + q0.z*wv[2] + q0.w*wv[3]
                 + q1.x*wv[4] + q1.y*wv[5] + q1.z*wv[6] + q1.w*wv[7]
                 + q2.x*wv[8] + q2.y*wv[9] + q2.z*wv[10] + q2.w*wv[11];
    float dt = softplusf(a);
    float u  = yrow[(size_t)j*DI];
    PackCv cv;
    cv.h[0] = (_Float16)dt;
    cv.h[1] = (_Float16)(dt*u);
    prow[(size_t)j*DI] = cv.u;
  }
}
__global__ __launch_bounds__(192) void k_pack(const float* dtsP, const float* Yin,
                                              const void* Wdt, const void* biasw,
                                              uint32* Pack, const void* alog){
  __shared__ float ds[64][RK];
  if(is_bf(alog)) pack_impl<true>(dtsP, Yin, Wdt, biasw, Pack, ds);
  else            pack_impl<false>(dtsP, Yin, Wdt, biasw, Pack, ds);
}

// ---------------- K3a: scan phase 1; n-split-2; stores S (16) and sdt (1) ------------------
template<bool BF>
__device__ void scan1_impl(const uint32* Pack, const float* BC, const void* Alog,
                           float* Sarr, float* Sdt, float (*bs)[NS]){
  const int blk = blockIdx.x;
  const int ch = blk % NCH;
  const int bk = blk / NCH;
  const int k  = bk % KKDIR;
  const int t  = threadIdx.x;
  const int d  = t >> 1;
  const int nh = t & 1;
  const int l0 = ch * CLEN;
  const int p0 = perm_p0(k, l0);
  const int ps = perm_ps(k);
  for(int idx = t; idx < CLEN*NS; idx += 384){
    int j = idx >> 4, n = idx & 15;
    bs[j][n] = BC[((size_t)bk*LLEN + p0 + ps*j)*32 + n];
  }
  float as2[8];
  {
    size_t arow = (size_t)(k*DI + d)*NS + nh*8;
    #pragma unroll
    for(int n = 0; n < 8; ++n) as2[n] = -__expf(ld1<BF>(Alog, arow + n)) * 1.44269504f;
  }
  float h[8];
  #pragma unroll
  for(int n = 0; n < 8; ++n) h[n] = 0.f;
  float sdt = 0.f;
  __syncthreads();
  const uint32* prow = Pack + (size_t)bk*LLEN*DI + d;
  int p = p0;
  #pragma unroll 2
  for(int j = 0; j < CLEN; ++j){
    PackCv cv; cv.u = prow[(size_t)p*DI];
    float dt  = (float)cv.h[0];
    float dtu = (float)cv.h[1];
    sdt += dt;
    float4 b0 = *(const float4*)&bs[j][nh*8];
    float4 b1 = *(const float4*)&bs[j][nh*8+4];
    h[0] = __builtin_amdgcn_exp2f(dt*as2[0])*h[0] + dtu*b0.x;
    h[1] = __builtin_amdgcn_exp2f(dt*as2[1])*h[1] + dtu*b0.y;
    h[2] = __builtin_amdgcn_exp2f(dt*as2[2])*h[2] + dtu*b0.z;
    h[3] = __builtin_amdgcn_exp2f(dt*as2[3])*h[3] + dtu*b0.w;
    h[4] = __builtin_amdgcn_exp2f(dt*as2[4])*h[4] + dtu*b1.x;
    h[5] = __builtin_amdgcn_exp2f(dt*as2[5])*h[5] + dtu*b1.y;
    h[6] = __builtin_amdgcn_exp2f(dt*as2[6])*h[6] + dtu*b1.z;
    h[7] = __builtin_amdgcn_exp2f(dt*as2[7])*h[7] + dtu*b1.w;
    p += ps;
  }
  size_t base = ((size_t)(bk*DI + d)*NCH + ch)*NS + nh*8;
  *(float4*)(Sarr+base)   = make_float4(h[0],h[1],h[2],h[3]);
  *(float4*)(Sarr+base+4) = make_float4(h[4],h[5],h[6],h[7]);
  if(nh == 0) Sdt[(size_t)(bk*DI + d)*NCH + ch] = sdt;
}
__global__ __launch_bounds__(384) void k_scan1(const uint32* Pack, const float* BC,
                                               const void* Alog, float* Sarr, float* Sdt){
  __shared__ float bs[CLEN][NS];
  if(is_bf(Alog)) scan1_impl<true>(Pack, BC, Alog, Sarr, Sdt, bs);
  else            scan1_impl<false>(Pack, BC, Alog, Sarr, Sdt, bs);
}

// ---------------- K3b: cross-chunk prefix; P recomputed from sdt --------------------------
template<bool BF>
__device__ void scan2_impl(float* Sarr, const float* Sdt, const void* Alog){
  int tid = blockIdx.x*256 + threadIdx.x;   // 49152 = B*K*D*N
  int n = tid & 15;
  int bkd = tid >> 4;
  int d = bkd % DI;
  int k = (bkd / DI) & 3;
  float as2 = -__expf(ld1<BF>(Alog, (size_t)(k*DI + d)*NS + n)) * 1.44269504f;
  float h = 0.f;
  for(int c = 0; c < NCH; ++c){
    size_t i = ((size_t)bkd*NCH + c)*NS + n;
    float s = Sarr[i];
    float p = __builtin_amdgcn_exp2f(as2 * Sdt[(size_t)bkd*NCH + c]);
    Sarr[i] = h;
    h = p*h + s;
  }
}
__global__ __launch_bounds__(256) void k_scan2(float* Sarr, const float* Sdt,
                                               const void* Alog){
  if(is_bf(Alog)) scan2_impl<true>(Sarr, Sdt, Alog);
  else            scan2_impl<false>(Sarr, Sdt, Alog);
}

// ---------------- K3c: scan phase 3; atomic-accumulate y at spatial pos -------------------
template<bool BF>
__device__ void scan3_impl(const uint32* Pack, const float* BC, const void* Alog,
                           const float* Hin, float* Acc, float (*bs)[32]){
  const int blk = blockIdx.x;
  const int ch = blk % NCH;
  const int bk = blk / NCH;
  const int k  = bk % KKDIR;
  const int b  = bk / KKDIR;
  const int t  = threadIdx.x;
  const int d  = t >> 1;
  const int nh = t & 1;
  const int l0 = ch * CLEN;
  const int p0 = perm_p0(k, l0);
  const int ps = perm_ps(k);
  for(int idx = t; idx < CLEN*32; idx += 384){
    int j = idx >> 5, n = idx & 31;
    bs[j][n] = BC[((size_t)bk*LLEN + p0 + ps*j)*32 + n];
  }
  float as2[8];
  {
    size_t arow = (size_t)(k*DI + d)*NS + nh*8;
    #pragma unroll
    for(int n = 0; n < 8; ++n) as2[n] = -__expf(ld1<BF>(Alog, arow + n)) * 1.44269504f;
  }
  float h[8];
  {
    size_t hbase = ((size_t)(bk*DI + d)*NCH + ch)*NS + nh*8;
    float4 h0 = *(const float4*)(Hin + hbase);
    float4 h1 = *(const float4*)(Hin + hbase + 4);
    h[0]=h0.x; h[1]=h0.y; h[2]=h0.z; h[3]=h0.w;
    h[4]=h1.x; h[5]=h1.y; h[6]=h1.z; h[7]=h1.w;
  }
  __syncthreads();
  const uint32* prow = Pack + (size_t)bk*LLEN*DI + d;
  float* arow = Acc + (size_t)b*LLEN*DI + d;
  int p = p0;
  #pragma unroll 2
  for(int j = 0; j < CLEN; ++j){
    PackCv cv; cv.u = prow[(size_t)p*DI];
    float dt  = (float)cv.h[0];
    float dtu = (float)cv.h[1];
    float4 b0 = *(const float4*)&bs[j][nh*8];
    float4 b1 = *(const float4*)&bs[j][nh*8+4];
    float4 c0 = *(const float4*)&bs[j][16+nh*8];
    float4 c1 = *(const float4*)&bs[j][16+nh*8+4];
    float y = 0.f;
    h[0] = __builtin_amdgcn_exp2f(dt*as2[0])*h[0] + dtu*b0.x;  y += h[0]*c0.x;
    h[1] = __builtin_amdgcn_exp2f(dt*as2[1])*h[1] + dtu*b0.y;  y += h[1]*c0.y;
    h[2] = __builtin_amdgcn_exp2f(dt*as2[2])*h[2] + dtu*b0.z;  y += h[2]*c0.z;
    h[3] = __builtin_amdgcn_exp2f(dt*as2[3])*h[3] + dtu*b0.w;  y += h[3]*c0.w;
    h[4] = __builtin_amdgcn_exp2f(dt*as2[4])*h[4] + dtu*b1.x;  y += h[4]*c1.x;
    h[5] = __builtin_amdgcn_exp2f(dt*as2[5])*h[5] + dtu*b1.y;  y += h[5]*c1.y;
    h[6] = __builtin_amdgcn_exp2f(dt*as2[6])*h[6] + dtu*b1.z;  y += h[6]*c1.z;
    h[7] = __builtin_amdgcn_exp2f(dt*as2[7])*h[7] + dtu*b1.w;  y += h[7]*c1.w;
    y += __shfl_xor(y, 1);
    if(nh == 0) atomicAdd(arow + (size_t)p*DI, y);  // involution: seq l emits at spatial p
    p += ps;
  }
}
__global__ __launch_bounds__(384) void k_scan3(const uint32* Pack, const float* BC,
                                               const void* Alog, const float* Hin,
                                               float* Acc){
  __shared__ float bs[CLEN][32];
  if(is_bf(Alog)) scan3_impl<true>(Pack, BC, Alog, Hin, Acc, bs);
  else            scan3_impl<false>(Pack, BC, Alog, Hin, Acc, bs);
}

// ---------------- K4: (+Ds*u) + LayerNorm + out_proj + store ------------------------------
template<bool BF>
__device__ void post_impl(const float* Acc, const float* Yin, const void* DsI,
                          const void* gamma, const void* beta,
                          const void* Wout, void* Out,
                          float (*ym)[YPAD], float* mu, float* rs,
                          float* gs, float* bt, float* dss){
  const int b     = blockIdx.x >> 7;
  const int l0    = ((blockIdx.x >> 1) & 63) << 6;
  const int chalf = blockIdx.x & 1;
  const int t     = threadIdx.x;
  if(t < DI){
    gs[t] = ld1<BF>(gamma, t); bt[t] = ld1<BF>(beta, t);
    float s = 0.f;
    #pragma unroll
    for(int k = 0; k < KKDIR; ++k) s += ld1<BF>(DsI, k*DI + t);
    dss[t] = s;
  }
  __syncthreads();
  // A: load 64x192 rows, adding the Ds*u term (u shared across directions at a site)
  for(int idx = t; idx < 64*48; idx += 256){
    int l = idx / 48, d4 = (idx % 48) * 4;
    size_t g = ((size_t)b*LLEN + l0 + l)*DI + d4;
    float4 v = *(const float4*)(Acc + g);
    float4 u = *(const float4*)(Yin + g);
    ym[l][d4]   = v.x + dss[d4]*u.x;
    ym[l][d4+1] = v.y + dss[d4+1]*u.y;
    ym[l][d4+2] = v.z + dss[d4+2]*u.z;
    ym[l][d4+3] = v.w + dss[d4+3]*u.w;
  }
  __syncthreads();
  const int row = t >> 2, sub = t & 3;
  {
    float s1 = 0.f, s2 = 0.f;
    #pragma unroll 8
    for(int j = 0; j < 48; ++j){
      float v = ym[row][sub*48 + j];
      s1 += v; s2 += v*v;
    }
    s1 += __shfl_xor(s1, 1); s2 += __shfl_xor(s2, 1);
    s1 += __shfl_xor(s1, 2); s2 += __shfl_xor(s2, 2);
    if(sub == 0){
      float mean = s1 * (1.f/192.f);
      float var  = s2 * (1.f/192.f) - mean*mean;
      mu[row] = mean;
      rs[row] = rsqrtf(var + 1e-5f);
    }
  }
  __syncthreads();
  {
    float m = mu[row], r = rs[row];
    #pragma unroll 8
    for(int j = 0; j < 48; ++j){
      int d = sub*48 + j;
      ym[row][d] = (ym[row][d] - m) * r * gs[d] + bt[d];
    }
  }
  __syncthreads();
  {
    const int lg = t & 15, cg = t >> 4;
    const int c0 = chalf*96 + cg*6;
    float acc[24];
    #pragma unroll
    for(int i = 0; i < 24; ++i) acc[i] = 0.f;
    for(int dd = 0; dd < DI; ++dd){
      float x0 = ym[lg*4+0][dd];
      float x1 = ym[lg*4+1][dd];
      float x2 = ym[lg*4+2][dd];
      float x3 = ym[lg*4+3][dd];
      size_t wrow = (size_t)dd*DI + c0;
      float4 wA = ld4<BF>(Wout, wrow);
      float2 wB = ld2<BF>(Wout, wrow + 4);
      float w[6] = {wA.x, wA.y, wA.z, wA.w, wB.x, wB.y};
      #pragma unroll
      for(int jc = 0; jc < 6; ++jc){
        acc[jc*4+0] += x0*w[jc];
        acc[jc*4+1] += x1*w[jc];
        acc[jc*4+2] += x2*w[jc];
        acc[jc*4+3] += x3*w[jc];
      }
    }
    #pragma unroll
    for(int jc = 0; jc < 6; ++jc){
      int c = c0 + jc;
      st4<BF>(Out, ((size_t)b*DI + c)*LLEN + l0 + lg*4,
              acc[jc*4+0], acc[jc*4+1], acc[jc*4+2], acc[jc*4+3]);
    }
  }
}
__global__ __launch_bounds__(256) void k_post(const float* Acc, const float* Yin,
                                              const void* DsI, const void* gamma,
                                              const void* beta, const void* Wout,
                                              void* Out, const void* alog){
  __shared__ float ym[64][YPAD];
  __shared__ float mu[64], rs[64];
  __shared__ float gs[DI], bt[DI], dss[DI];
  if(is_bf(alog)) post_impl<true>(Acc, Yin, DsI, gamma, beta, Wout, Out, ym, mu, rs, gs, bt, dss);
  else            post_impl<false>(Acc, Yin, DsI, gamma, beta, Wout, Out, ym, mu, rs, gs, bt, dss);
}

extern "C" void kernel_launch(void* const* d_in, const int* in_sizes, int n_in,
                              void* d_out, int out_size, void* d_ws, size_t ws_size,
                              hipStream_t stream){
  (void)in_sizes; (void)n_in; (void)out_size; (void)ws_size;
  const void* x    = d_in[0];
  const void* y    = d_in[1];
  const void* wx   = d_in[2];
  const void* wy   = d_in[3];
  const void* xpw  = d_in[4];
  const void* wdt  = d_in[5];
  const void* dtb  = d_in[6];
  const void* alog = d_in[7];
  const void* dsv  = d_in[8];
  const void* gam  = d_in[9];
  const void* bet  = d_in[10];
  const void* wout = d_in[11];

  float* ws   = (float*)d_ws;
  float* yin  = ws;                                            // BLD (12.6MB)
  float* dtsP = yin  + BLD;                                    // B*K*L*12 (3.1MB)
  float* bc   = dtsP + (size_t)BATCH*KKDIR*LLEN*RK;            // B*K*L*32 (8.4MB)
  float* acc  = bc   + (size_t)BATCH*KKDIR*LLEN*32;            // BLD (12.6MB)
  float* sarr = acc  + BLD;                                    // B*K*D*NCH*NS (12.6MB)
  float* sdt  = sarr + (size_t)BATCH*KKDIR*DI*NCH*NS;          // B*K*D*NCH (0.8MB)
  float* xreg = sdt  + (size_t)BATCH*KKDIR*DI*NCH;             // union region:
  float* xin  = xreg;                                          //   fp32 B*L*D (12.6MB), dead after k_proj
  uint32* pack = (uint32*)xreg;                                //   u32 B*K*L*D (50.3MB), written after
  // total ~= 100.5 MB

  k_inproj<<<512, 256, 0, stream>>>(x, y, wx, wy, xin, yin, alog);
  k_proj<<<512, 256, 0, stream>>>(xin, xpw, dtsP, bc, acc, alog);
  k_pack<<<BATCH*KKDIR*64, 192, 0, stream>>>(dtsP, yin, wdt, dtb, pack, alog);
  k_scan1<<<BATCH*KKDIR*NCH, 384, 0, stream>>>(pack, bc, alog, sarr, sdt);
  k_scan2<<<192, 256, 0, stream>>>(sarr, sdt, alog);
  k_scan3<<<BATCH*KKDIR*NCH, 384, 0, stream>>>(pack, bc, alog, sarr, acc);
  k_post<<<BATCH*64*2, 256, 0, stream>>>(acc, yin, dsv, gam, bet, wout, d_out, alog);
}